// Round 3
// baseline (748.361 us; speedup 1.0000x reference)
//
#include <hip/hip_runtime.h>
#include <hip/hip_bf16.h>

typedef unsigned int uint32;

// ---------------------------------------------------------------------------
// Graph preprocessing: degree count -> exclusive scan -> CSR fill (by target)
// ---------------------------------------------------------------------------

__global__ __launch_bounds__(256)
void zero_cnt_kernel(uint32* __restrict__ cnt, int n) {
    int i = blockIdx.x * 256 + threadIdx.x;
    if (i < n) cnt[i] = 0u;
}

__global__ __launch_bounds__(256)
void count_kernel(const int* __restrict__ col, int n_edges, uint32* __restrict__ cnt) {
    int e = blockIdx.x * 256 + threadIdx.x;
    if (e < n_edges) atomicAdd(&cnt[col[e]], 1u);
}

// Single-workgroup chunked Hillis-Steele exclusive scan (n ~= 50k -> ~49 chunks)
__global__ __launch_bounds__(1024)
void scan_kernel(const uint32* __restrict__ cnt, uint32* __restrict__ offs, int n) {
    __shared__ uint32 sh[1024];
    __shared__ uint32 carry_sh;
    if (threadIdx.x == 0) carry_sh = 0u;
    __syncthreads();
    for (int base = 0; base < n; base += 1024) {
        int i = base + (int)threadIdx.x;
        uint32 v = (i < n) ? cnt[i] : 0u;
        sh[threadIdx.x] = v;
        __syncthreads();
        for (int off = 1; off < 1024; off <<= 1) {
            uint32 t = (threadIdx.x >= (unsigned)off) ? sh[threadIdx.x - off] : 0u;
            __syncthreads();
            sh[threadIdx.x] += t;
            __syncthreads();
        }
        uint32 c = carry_sh;
        if (i < n) offs[i] = c + sh[threadIdx.x] - v;   // exclusive
        __syncthreads();
        if (threadIdx.x == 1023) carry_sh = c + sh[1023];
        __syncthreads();
    }
    if (threadIdx.x == 0) offs[n] = carry_sh;
}

__global__ __launch_bounds__(256)
void dis_cursor_kernel(const uint32* __restrict__ cnt, float* __restrict__ dis,
                       uint32* __restrict__ cursor, int n) {
    int i = blockIdx.x * 256 + threadIdx.x;
    if (i < n) {
        // self-loop => deg = cnt + 1 >= 1, so rsqrt is always finite
        dis[i] = rsqrtf((float)(cnt[i] + 1u));
        cursor[i] = 0u;
    }
}

__global__ __launch_bounds__(256)
void fill_kernel(const int* __restrict__ row, const int* __restrict__ col, int n_edges,
                 const uint32* __restrict__ offs, uint32* __restrict__ cursor,
                 uint32* __restrict__ csr) {
    int e = blockIdx.x * 256 + threadIdx.x;
    if (e < n_edges) {
        int c = col[e];
        uint32 p = offs[c] + atomicAdd(&cursor[c], 1u);
        csr[p] = (uint32)row[e];
    }
}

// ---------------------------------------------------------------------------
// hs[r][c] = dis[r] * sum_k A[gather(r)][k] * W[k][c]      (A is N x 128)
// W split into two half-panels (cols 0..63 from W0, 64..127 from W1b), each
// row-major with stride `wstride`. 16 threads/row, 8 cols/thread.
// ---------------------------------------------------------------------------
__global__ __launch_bounds__(256)
void gemm_scale_kernel(const float* __restrict__ A, const int* __restrict__ gather,
                       const float* __restrict__ W0, const float* __restrict__ W1b,
                       int wstride, const float* __restrict__ dis,
                       float* __restrict__ out, int n_rows) {
    int t = blockIdx.x * 256 + threadIdx.x;
    int r = t >> 4;
    if (r >= n_rows) return;
    int c8 = (t & 15) * 8;

    int ra = gather ? gather[r] : r;
    const float* a = A + (size_t)ra * 128;
    const float* wb = (c8 < 64) ? (W0 + c8) : (W1b + (c8 - 64));

    float4 acc0 = make_float4(0.f, 0.f, 0.f, 0.f);
    float4 acc1 = make_float4(0.f, 0.f, 0.f, 0.f);

    for (int k = 0; k < 128; k += 4) {
        float4 av = *(const float4*)(a + k);
        const float* w = wb + (size_t)k * wstride;
        #pragma unroll
        for (int kk = 0; kk < 4; kk++) {
            float s = (kk == 0) ? av.x : (kk == 1) ? av.y : (kk == 2) ? av.z : av.w;
            float4 w0 = *(const float4*)(w);
            float4 w1 = *(const float4*)(w + 4);
            acc0.x = fmaf(s, w0.x, acc0.x);
            acc0.y = fmaf(s, w0.y, acc0.y);
            acc0.z = fmaf(s, w0.z, acc0.z);
            acc0.w = fmaf(s, w0.w, acc0.w);
            acc1.x = fmaf(s, w1.x, acc1.x);
            acc1.y = fmaf(s, w1.y, acc1.y);
            acc1.z = fmaf(s, w1.z, acc1.z);
            acc1.w = fmaf(s, w1.w, acc1.w);
            w += wstride;
        }
    }
    float d = dis[r];
    float* o = out + (size_t)r * 128 + c8;
    *(float4*)(o)     = make_float4(d * acc0.x, d * acc0.y, d * acc0.z, d * acc0.w);
    *(float4*)(o + 4) = make_float4(d * acc1.x, d * acc1.y, d * acc1.z, d * acc1.w);
}

// ---------------------------------------------------------------------------
// Aggregation: one wave per target node v.
//   acc = hs[v] (self-loop) + sum over CSR edges hs[row_e]
//   out = relu(dis[v]*acc + b)          (layer 1)
// Each lane owns 2 features (float2), so a row gather is one coalesced 512B access.
// ---------------------------------------------------------------------------
__global__ __launch_bounds__(256)
void agg_relu_kernel(const float* __restrict__ hs, const uint32* __restrict__ offs,
                     const uint32* __restrict__ csr, const float* __restrict__ dis,
                     const float* __restrict__ bias, float* __restrict__ out, int n_nodes) {
    int wid = (blockIdx.x * 256 + (int)threadIdx.x) >> 6;
    int lane = threadIdx.x & 63;
    if (wid >= n_nodes) return;

    const float2* base = (const float2*)hs;
    float2 acc = base[(size_t)wid * 64 + lane];     // self-loop term
    int beg = (int)offs[wid], end = (int)offs[wid + 1];

    int j = beg;
    for (; j + 4 <= end; j += 4) {
        uint32 r0 = csr[j], r1 = csr[j + 1], r2 = csr[j + 2], r3 = csr[j + 3];
        float2 a0 = base[(size_t)r0 * 64 + lane];
        float2 a1 = base[(size_t)r1 * 64 + lane];
        float2 a2 = base[(size_t)r2 * 64 + lane];
        float2 a3 = base[(size_t)r3 * 64 + lane];
        acc.x += (a0.x + a1.x) + (a2.x + a3.x);
        acc.y += (a0.y + a1.y) + (a2.y + a3.y);
    }
    for (; j < end; ++j) {
        uint32 r = csr[j];
        float2 a = base[(size_t)r * 64 + lane];
        acc.x += a.x; acc.y += a.y;
    }

    float d = dis[wid];
    float2 b = ((const float2*)bias)[lane];
    float2 o;
    o.x = fmaxf(fmaf(d, acc.x, b.x), 0.f);
    o.y = fmaxf(fmaf(d, acc.y, b.y), 0.f);
    ((float2*)out)[(size_t)wid * 64 + lane] = o;
}

// Layer 2: features 0..63 -> mu (+b_mu), 64..127 -> logvar (+b_logvar), no relu.
__global__ __launch_bounds__(256)
void agg_out_kernel(const float* __restrict__ hs, const uint32* __restrict__ offs,
                    const uint32* __restrict__ csr, const float* __restrict__ dis,
                    const float* __restrict__ bmu, const float* __restrict__ blv,
                    float* __restrict__ out_mu, float* __restrict__ out_lv, int n_nodes) {
    int wid = (blockIdx.x * 256 + (int)threadIdx.x) >> 6;
    int lane = threadIdx.x & 63;
    if (wid >= n_nodes) return;

    const float2* base = (const float2*)hs;
    float2 acc = base[(size_t)wid * 64 + lane];
    int beg = (int)offs[wid], end = (int)offs[wid + 1];

    int j = beg;
    for (; j + 4 <= end; j += 4) {
        uint32 r0 = csr[j], r1 = csr[j + 1], r2 = csr[j + 2], r3 = csr[j + 3];
        float2 a0 = base[(size_t)r0 * 64 + lane];
        float2 a1 = base[(size_t)r1 * 64 + lane];
        float2 a2 = base[(size_t)r2 * 64 + lane];
        float2 a3 = base[(size_t)r3 * 64 + lane];
        acc.x += (a0.x + a1.x) + (a2.x + a3.x);
        acc.y += (a0.y + a1.y) + (a2.y + a3.y);
    }
    for (; j < end; ++j) {
        uint32 r = csr[j];
        float2 a = base[(size_t)r * 64 + lane];
        acc.x += a.x; acc.y += a.y;
    }

    float d = dis[wid];
    if (lane < 32) {
        float2 b = ((const float2*)bmu)[lane];
        float2 o = make_float2(fmaf(d, acc.x, b.x), fmaf(d, acc.y, b.y));
        ((float2*)out_mu)[(size_t)wid * 32 + lane] = o;
    } else {
        int l2 = lane - 32;
        float2 b = ((const float2*)blv)[l2];
        float2 o = make_float2(fmaf(d, acc.x, b.x), fmaf(d, acc.y, b.y));
        ((float2*)out_lv)[(size_t)wid * 32 + l2] = o;
    }
}

// ---------------------------------------------------------------------------

extern "C" void kernel_launch(void* const* d_in, const int* in_sizes, int n_in,
                              void* d_out, int out_size, void* d_ws, size_t ws_size,
                              hipStream_t stream) {
    const int*   x   = (const int*)d_in[0];
    const int*   ei  = (const int*)d_in[1];
    const float* emb = (const float*)d_in[2];
    const float* W1  = (const float*)d_in[3];
    const float* b1  = (const float*)d_in[4];
    const float* Wmu = (const float*)d_in[5];
    const float* bmu = (const float*)d_in[6];
    const float* Wlv = (const float*)d_in[7];
    const float* blv = (const float*)d_in[8];

    int n_nodes = in_sizes[0];
    int n_edges = in_sizes[1] / 2;
    const int* row = ei;              // source nodes
    const int* col = ei + n_edges;    // target nodes (aggregation index)

    // Workspace carve-out (all 256B-aligned). Total ~58.4 MB.
    char* wp = (char*)d_ws;
    auto carve = [&wp](size_t bytes) -> char* {
        char* p = wp;
        wp += (bytes + 255) & ~(size_t)255;
        return p;
    };
    uint32* cnt    = (uint32*)carve((size_t)n_nodes * 4);
    uint32* cursor = (uint32*)carve((size_t)n_nodes * 4);
    uint32* offs   = (uint32*)carve(((size_t)n_nodes + 1) * 4);
    float*  dis    = (float*) carve((size_t)n_nodes * 4);
    uint32* csr    = (uint32*)carve((size_t)n_edges * 4);
    float*  bufA   = (float*) carve((size_t)n_nodes * 128 * 4);   // hs
    float*  bufB   = (float*) carve((size_t)n_nodes * 128 * 4);   // h1

    int gb_n = (n_nodes + 255) / 256;
    int gb_e = (n_edges + 255) / 256;

    hipLaunchKernelGGL(zero_cnt_kernel, dim3(gb_n), dim3(256), 0, stream, cnt, n_nodes);
    hipLaunchKernelGGL(count_kernel, dim3(gb_e), dim3(256), 0, stream, col, n_edges, cnt);
    hipLaunchKernelGGL(scan_kernel, dim3(1), dim3(1024), 0, stream, cnt, offs, n_nodes);
    hipLaunchKernelGGL(dis_cursor_kernel, dim3(gb_n), dim3(256), 0, stream, cnt, dis, cursor, n_nodes);
    hipLaunchKernelGGL(fill_kernel, dim3(gb_e), dim3(256), 0, stream, row, col, n_edges, offs, cursor, csr);

    int gemm_blocks = (n_nodes * 16 + 255) / 256;
    int agg_blocks  = (n_nodes + 3) / 4;

    // Layer 1: hs = (emb[x] @ W1) * dis ; h1 = relu(dis * (agg + self) + b1)
    hipLaunchKernelGGL(gemm_scale_kernel, dim3(gemm_blocks), dim3(256), 0, stream,
                       emb, x, W1, W1 + 64, 128, dis, bufA, n_nodes);
    hipLaunchKernelGGL(agg_relu_kernel, dim3(agg_blocks), dim3(256), 0, stream,
                       bufA, offs, csr, dis, b1, bufB, n_nodes);

    // Layer 2 (mu and logvar fused into one 128-wide pass)
    hipLaunchKernelGGL(gemm_scale_kernel, dim3(gemm_blocks), dim3(256), 0, stream,
                       bufB, (const int*)nullptr, Wmu, Wlv, 64, dis, bufA, n_nodes);

    float* out_mu = (float*)d_out;
    float* out_lv = out_mu + (size_t)n_nodes * 64;
    hipLaunchKernelGGL(agg_out_kernel, dim3(agg_blocks), dim3(256), 0, stream,
                       bufA, offs, csr, dis, bmu, blv, out_mu, out_lv, n_nodes);
}

// Round 4
// 574.341 us; speedup vs baseline: 1.3030x; 1.3030x over previous
//
#include <hip/hip_runtime.h>
#include <hip/hip_bf16.h>

typedef unsigned int uint32;

// ---------------------------------------------------------------------------
// Graph preprocessing: degree count -> hierarchical exclusive scan -> CSR fill
// ---------------------------------------------------------------------------

__global__ __launch_bounds__(256)
void zero_cnt_kernel(uint32* __restrict__ cnt, int n) {
    int i = blockIdx.x * 256 + threadIdx.x;
    if (i < n) cnt[i] = 0u;
}

__global__ __launch_bounds__(256)
void count_kernel(const int* __restrict__ col, int n_edges, uint32* __restrict__ cnt) {
    int e = blockIdx.x * 256 + threadIdx.x;
    if (e < n_edges) atomicAdd(&cnt[col[e]], 1u);
}

// Stage 1: per-block (256 elems) exclusive scan + per-block sum.
__global__ __launch_bounds__(256)
void scan_blk_kernel(const uint32* __restrict__ cnt, uint32* __restrict__ partial,
                     uint32* __restrict__ blk_sums, int n) {
    __shared__ uint32 sh[256];
    int i = blockIdx.x * 256 + (int)threadIdx.x;
    uint32 v = (i < n) ? cnt[i] : 0u;
    sh[threadIdx.x] = v;
    __syncthreads();
    for (int off = 1; off < 256; off <<= 1) {
        uint32 t = (threadIdx.x >= (unsigned)off) ? sh[threadIdx.x - off] : 0u;
        __syncthreads();
        sh[threadIdx.x] += t;
        __syncthreads();
    }
    if (i < n) partial[i] = sh[threadIdx.x] - v;      // exclusive within block
    if (threadIdx.x == 255) blk_sums[blockIdx.x] = sh[255];
}

// Stage 2: one block scans the block sums (nb <= 1024).
__global__ __launch_bounds__(1024)
void scan_sums_kernel(const uint32* __restrict__ blk_sums, uint32* __restrict__ blk_offs, int nb) {
    __shared__ uint32 sh[1024];
    uint32 v = ((int)threadIdx.x < nb) ? blk_sums[threadIdx.x] : 0u;
    sh[threadIdx.x] = v;
    __syncthreads();
    for (int off = 1; off < 1024; off <<= 1) {
        uint32 t = (threadIdx.x >= (unsigned)off) ? sh[threadIdx.x - off] : 0u;
        __syncthreads();
        sh[threadIdx.x] += t;
        __syncthreads();
    }
    if ((int)threadIdx.x < nb) blk_offs[threadIdx.x] = sh[threadIdx.x] - v;
}

// Stage 3: offs = partial + blk_offs; fused dis = rsqrt(deg+1) and cursor = 0.
__global__ __launch_bounds__(256)
void scan_add_kernel(const uint32* __restrict__ partial, const uint32* __restrict__ blk_offs,
                     const uint32* __restrict__ cnt, uint32* __restrict__ offs,
                     float* __restrict__ dis, uint32* __restrict__ cursor,
                     int n, int n_edges) {
    int i = blockIdx.x * 256 + (int)threadIdx.x;
    if (i < n) {
        offs[i] = partial[i] + blk_offs[blockIdx.x];
        dis[i] = rsqrtf((float)(cnt[i] + 1u));   // self-loop => deg >= 1
        cursor[i] = 0u;
    }
    if (i == 0) offs[n] = (uint32)n_edges;       // sum of cnt == n_edges
}

__global__ __launch_bounds__(256)
void fill_kernel(const int* __restrict__ row, const int* __restrict__ col, int n_edges,
                 const uint32* __restrict__ offs, uint32* __restrict__ cursor,
                 uint32* __restrict__ csr) {
    int e = blockIdx.x * 256 + threadIdx.x;
    if (e < n_edges) {
        int c = col[e];
        uint32 p = offs[c] + atomicAdd(&cursor[c], 1u);
        csr[p] = (uint32)row[e];
    }
}

// ---------------------------------------------------------------------------
// hs[r][c] = dis[r] * sum_k A[gather(r)][k] * W[k][c]      (A is N x 128)
// W split into two half-panels (cols 0..63 from W0, 64..127 from W1b), each
// row-major with stride `wstride`.
// Register blocking: each thread computes 4 rows x 8 cols (16 threads/row-group
// cover 128 cols; 16 groups/block -> 64 rows/block). Per k-chunk of 4:
// 12 float4 loads feed 128 FMAs.
// ---------------------------------------------------------------------------
__global__ __launch_bounds__(256)
void gemm_scale_kernel(const float* __restrict__ A, const int* __restrict__ gather,
                       const float* __restrict__ W0, const float* __restrict__ W1b,
                       int wstride, const float* __restrict__ dis,
                       float* __restrict__ out, int n_rows) {
    int grp = threadIdx.x >> 4;            // 0..15
    int c8  = (threadIdx.x & 15) * 8;      // col block
    int r0  = blockIdx.x * 64 + grp * 4;   // first of 4 rows
    if (r0 >= n_rows) return;

    const float* wb = (c8 < 64) ? (W0 + c8) : (W1b + (c8 - 64));

    // Clamped row pointers (stores are guarded; loads clamp to stay in-bounds)
    const float* ap[4];
    #pragma unroll
    for (int i = 0; i < 4; i++) {
        int r = r0 + i;
        if (r > n_rows - 1) r = n_rows - 1;
        int ra = gather ? gather[r] : r;
        ap[i] = A + (size_t)ra * 128;
    }

    float acc[4][8];
    #pragma unroll
    for (int i = 0; i < 4; i++)
        #pragma unroll
        for (int j = 0; j < 8; j++) acc[i][j] = 0.f;

    for (int k = 0; k < 128; k += 4) {
        float4 av[4];
        #pragma unroll
        for (int i = 0; i < 4; i++) av[i] = *(const float4*)(ap[i] + k);

        const float* w = wb + (size_t)k * wstride;
        #pragma unroll
        for (int kk = 0; kk < 4; kk++) {
            float4 w0 = *(const float4*)(w);
            float4 w1 = *(const float4*)(w + 4);
            #pragma unroll
            for (int i = 0; i < 4; i++) {
                float s = (kk == 0) ? av[i].x : (kk == 1) ? av[i].y
                        : (kk == 2) ? av[i].z : av[i].w;
                acc[i][0] = fmaf(s, w0.x, acc[i][0]);
                acc[i][1] = fmaf(s, w0.y, acc[i][1]);
                acc[i][2] = fmaf(s, w0.z, acc[i][2]);
                acc[i][3] = fmaf(s, w0.w, acc[i][3]);
                acc[i][4] = fmaf(s, w1.x, acc[i][4]);
                acc[i][5] = fmaf(s, w1.y, acc[i][5]);
                acc[i][6] = fmaf(s, w1.z, acc[i][6]);
                acc[i][7] = fmaf(s, w1.w, acc[i][7]);
            }
            w += wstride;
        }
    }

    #pragma unroll
    for (int i = 0; i < 4; i++) {
        int r = r0 + i;
        if (r < n_rows) {
            float d = dis[r];
            float* o = out + (size_t)r * 128 + c8;
            *(float4*)(o)     = make_float4(d * acc[i][0], d * acc[i][1],
                                            d * acc[i][2], d * acc[i][3]);
            *(float4*)(o + 4) = make_float4(d * acc[i][4], d * acc[i][5],
                                            d * acc[i][6], d * acc[i][7]);
        }
    }
}

// ---------------------------------------------------------------------------
// Aggregation: one wave per target node v.
//   acc = hs[v] (self-loop) + sum over CSR edges hs[row_e]
//   out = relu(dis[v]*acc + b)          (layer 1)
// Each lane owns 2 features (float2), so a row gather is one coalesced 512B access.
// ---------------------------------------------------------------------------
__global__ __launch_bounds__(256)
void agg_relu_kernel(const float* __restrict__ hs, const uint32* __restrict__ offs,
                     const uint32* __restrict__ csr, const float* __restrict__ dis,
                     const float* __restrict__ bias, float* __restrict__ out, int n_nodes) {
    int wid = (blockIdx.x * 256 + (int)threadIdx.x) >> 6;
    int lane = threadIdx.x & 63;
    if (wid >= n_nodes) return;

    const float2* base = (const float2*)hs;
    float2 acc = base[(size_t)wid * 64 + lane];     // self-loop term
    int beg = (int)offs[wid], end = (int)offs[wid + 1];

    int j = beg;
    for (; j + 4 <= end; j += 4) {
        uint32 r0 = csr[j], r1 = csr[j + 1], r2 = csr[j + 2], r3 = csr[j + 3];
        float2 a0 = base[(size_t)r0 * 64 + lane];
        float2 a1 = base[(size_t)r1 * 64 + lane];
        float2 a2 = base[(size_t)r2 * 64 + lane];
        float2 a3 = base[(size_t)r3 * 64 + lane];
        acc.x += (a0.x + a1.x) + (a2.x + a3.x);
        acc.y += (a0.y + a1.y) + (a2.y + a3.y);
    }
    for (; j < end; ++j) {
        uint32 r = csr[j];
        float2 a = base[(size_t)r * 64 + lane];
        acc.x += a.x; acc.y += a.y;
    }

    float d = dis[wid];
    float2 b = ((const float2*)bias)[lane];
    float2 o;
    o.x = fmaxf(fmaf(d, acc.x, b.x), 0.f);
    o.y = fmaxf(fmaf(d, acc.y, b.y), 0.f);
    ((float2*)out)[(size_t)wid * 64 + lane] = o;
}

// Layer 2: features 0..63 -> mu (+b_mu), 64..127 -> logvar (+b_logvar), no relu.
__global__ __launch_bounds__(256)
void agg_out_kernel(const float* __restrict__ hs, const uint32* __restrict__ offs,
                    const uint32* __restrict__ csr, const float* __restrict__ dis,
                    const float* __restrict__ bmu, const float* __restrict__ blv,
                    float* __restrict__ out_mu, float* __restrict__ out_lv, int n_nodes) {
    int wid = (blockIdx.x * 256 + (int)threadIdx.x) >> 6;
    int lane = threadIdx.x & 63;
    if (wid >= n_nodes) return;

    const float2* base = (const float2*)hs;
    float2 acc = base[(size_t)wid * 64 + lane];
    int beg = (int)offs[wid], end = (int)offs[wid + 1];

    int j = beg;
    for (; j + 4 <= end; j += 4) {
        uint32 r0 = csr[j], r1 = csr[j + 1], r2 = csr[j + 2], r3 = csr[j + 3];
        float2 a0 = base[(size_t)r0 * 64 + lane];
        float2 a1 = base[(size_t)r1 * 64 + lane];
        float2 a2 = base[(size_t)r2 * 64 + lane];
        float2 a3 = base[(size_t)r3 * 64 + lane];
        acc.x += (a0.x + a1.x) + (a2.x + a3.x);
        acc.y += (a0.y + a1.y) + (a2.y + a3.y);
    }
    for (; j < end; ++j) {
        uint32 r = csr[j];
        float2 a = base[(size_t)r * 64 + lane];
        acc.x += a.x; acc.y += a.y;
    }

    float d = dis[wid];
    if (lane < 32) {
        float2 b = ((const float2*)bmu)[lane];
        float2 o = make_float2(fmaf(d, acc.x, b.x), fmaf(d, acc.y, b.y));
        ((float2*)out_mu)[(size_t)wid * 32 + lane] = o;
    } else {
        int l2 = lane - 32;
        float2 b = ((const float2*)blv)[l2];
        float2 o = make_float2(fmaf(d, acc.x, b.x), fmaf(d, acc.y, b.y));
        ((float2*)out_lv)[(size_t)wid * 32 + l2] = o;
    }
}

// ---------------------------------------------------------------------------

extern "C" void kernel_launch(void* const* d_in, const int* in_sizes, int n_in,
                              void* d_out, int out_size, void* d_ws, size_t ws_size,
                              hipStream_t stream) {
    const int*   x   = (const int*)d_in[0];
    const int*   ei  = (const int*)d_in[1];
    const float* emb = (const float*)d_in[2];
    const float* W1  = (const float*)d_in[3];
    const float* b1  = (const float*)d_in[4];
    const float* Wmu = (const float*)d_in[5];
    const float* bmu = (const float*)d_in[6];
    const float* Wlv = (const float*)d_in[7];
    const float* blv = (const float*)d_in[8];

    int n_nodes = in_sizes[0];
    int n_edges = in_sizes[1] / 2;
    const int* row = ei;              // source nodes
    const int* col = ei + n_edges;    // target nodes (aggregation index)

    // Workspace carve-out (all 256B-aligned).
    char* wp = (char*)d_ws;
    auto carve = [&wp](size_t bytes) -> char* {
        char* p = wp;
        wp += (bytes + 255) & ~(size_t)255;
        return p;
    };
    int nb = (n_nodes + 255) / 256;   // scan blocks (196 for 50k, <= 1024)

    uint32* cnt     = (uint32*)carve((size_t)n_nodes * 4);
    uint32* cursor  = (uint32*)carve((size_t)n_nodes * 4);
    uint32* offs    = (uint32*)carve(((size_t)n_nodes + 1) * 4);
    uint32* partial = (uint32*)carve((size_t)n_nodes * 4);
    uint32* bsums   = (uint32*)carve((size_t)nb * 4);
    uint32* boffs   = (uint32*)carve((size_t)nb * 4);
    float*  dis     = (float*) carve((size_t)n_nodes * 4);
    uint32* csr     = (uint32*)carve((size_t)n_edges * 4);
    float*  bufA    = (float*) carve((size_t)n_nodes * 128 * 4);   // hs
    float*  bufB    = (float*) carve((size_t)n_nodes * 128 * 4);   // h1

    int gb_e = (n_edges + 255) / 256;

    hipLaunchKernelGGL(zero_cnt_kernel, dim3(nb), dim3(256), 0, stream, cnt, n_nodes);
    hipLaunchKernelGGL(count_kernel, dim3(gb_e), dim3(256), 0, stream, col, n_edges, cnt);
    hipLaunchKernelGGL(scan_blk_kernel, dim3(nb), dim3(256), 0, stream, cnt, partial, bsums, n_nodes);
    hipLaunchKernelGGL(scan_sums_kernel, dim3(1), dim3(1024), 0, stream, bsums, boffs, nb);
    hipLaunchKernelGGL(scan_add_kernel, dim3(nb), dim3(256), 0, stream,
                       partial, boffs, cnt, offs, dis, cursor, n_nodes, n_edges);
    hipLaunchKernelGGL(fill_kernel, dim3(gb_e), dim3(256), 0, stream, row, col, n_edges, offs, cursor, csr);

    int gemm_blocks = (n_nodes + 63) / 64;
    int agg_blocks  = (n_nodes + 3) / 4;

    // Layer 1: hs = (emb[x] @ W1) * dis ; h1 = relu(dis * (agg + self) + b1)
    hipLaunchKernelGGL(gemm_scale_kernel, dim3(gemm_blocks), dim3(256), 0, stream,
                       emb, x, W1, W1 + 64, 128, dis, bufA, n_nodes);
    hipLaunchKernelGGL(agg_relu_kernel, dim3(agg_blocks), dim3(256), 0, stream,
                       bufA, offs, csr, dis, b1, bufB, n_nodes);

    // Layer 2 (mu and logvar fused into one 128-wide pass)
    hipLaunchKernelGGL(gemm_scale_kernel, dim3(gemm_blocks), dim3(256), 0, stream,
                       bufB, (const int*)nullptr, Wmu, Wlv, 64, dis, bufA, n_nodes);

    float* out_mu = (float*)d_out;
    float* out_lv = out_mu + (size_t)n_nodes * 64;
    hipLaunchKernelGGL(agg_out_kernel, dim3(agg_blocks), dim3(256), 0, stream,
                       bufA, offs, csr, dis, bmu, blv, out_mu, out_lv, n_nodes);
}

// Round 5
// 495.783 us; speedup vs baseline: 1.5095x; 1.1585x over previous
//
#include <hip/hip_runtime.h>
#include <hip/hip_bf16.h>

typedef unsigned int uint32;

// ---------------------------------------------------------------------------
// Graph preprocessing: degree count -> hierarchical exclusive scan -> CSR fill
// ---------------------------------------------------------------------------

__global__ __launch_bounds__(256)
void zero_cnt_kernel(uint32* __restrict__ cnt, int n) {
    int i = blockIdx.x * 256 + threadIdx.x;
    if (i < n) cnt[i] = 0u;
}

__global__ __launch_bounds__(256)
void count_kernel(const int* __restrict__ col, int n_edges, uint32* __restrict__ cnt) {
    int e = blockIdx.x * 256 + threadIdx.x;
    if (e < n_edges) atomicAdd(&cnt[col[e]], 1u);
}

// Stage 1: per-block (256 elems) exclusive scan + per-block sum.
__global__ __launch_bounds__(256)
void scan_blk_kernel(const uint32* __restrict__ cnt, uint32* __restrict__ partial,
                     uint32* __restrict__ blk_sums, int n) {
    __shared__ uint32 sh[256];
    int i = blockIdx.x * 256 + (int)threadIdx.x;
    uint32 v = (i < n) ? cnt[i] : 0u;
    sh[threadIdx.x] = v;
    __syncthreads();
    for (int off = 1; off < 256; off <<= 1) {
        uint32 t = (threadIdx.x >= (unsigned)off) ? sh[threadIdx.x - off] : 0u;
        __syncthreads();
        sh[threadIdx.x] += t;
        __syncthreads();
    }
    if (i < n) partial[i] = sh[threadIdx.x] - v;      // exclusive within block
    if (threadIdx.x == 255) blk_sums[blockIdx.x] = sh[255];
}

// Stage 2: one block scans the block sums (nb <= 1024).
__global__ __launch_bounds__(1024)
void scan_sums_kernel(const uint32* __restrict__ blk_sums, uint32* __restrict__ blk_offs, int nb) {
    __shared__ uint32 sh[1024];
    uint32 v = ((int)threadIdx.x < nb) ? blk_sums[threadIdx.x] : 0u;
    sh[threadIdx.x] = v;
    __syncthreads();
    for (int off = 1; off < 1024; off <<= 1) {
        uint32 t = (threadIdx.x >= (unsigned)off) ? sh[threadIdx.x - off] : 0u;
        __syncthreads();
        sh[threadIdx.x] += t;
        __syncthreads();
    }
    if ((int)threadIdx.x < nb) blk_offs[threadIdx.x] = sh[threadIdx.x] - v;
}

// Stage 3: offs = partial + blk_offs; fused dis = rsqrt(deg+1) and cursor = 0.
__global__ __launch_bounds__(256)
void scan_add_kernel(const uint32* __restrict__ partial, const uint32* __restrict__ blk_offs,
                     const uint32* __restrict__ cnt, uint32* __restrict__ offs,
                     float* __restrict__ dis, uint32* __restrict__ cursor,
                     int n, int n_edges) {
    int i = blockIdx.x * 256 + (int)threadIdx.x;
    if (i < n) {
        offs[i] = partial[i] + blk_offs[blockIdx.x];
        dis[i] = rsqrtf((float)(cnt[i] + 1u));   // self-loop => deg >= 1
        cursor[i] = 0u;
    }
    if (i == 0) offs[n] = (uint32)n_edges;       // sum of cnt == n_edges
}

__global__ __launch_bounds__(256)
void fill_kernel(const int* __restrict__ row, const int* __restrict__ col, int n_edges,
                 const uint32* __restrict__ offs, uint32* __restrict__ cursor,
                 uint32* __restrict__ csr) {
    int e = blockIdx.x * 256 + threadIdx.x;
    if (e < n_edges) {
        int c = col[e];
        uint32 p = offs[c] + atomicAdd(&cursor[c], 1u);
        csr[p] = (uint32)row[e];
    }
}

// ---------------------------------------------------------------------------
// bf16 helpers (RNE, deterministic)
// ---------------------------------------------------------------------------
static __device__ __forceinline__ uint32 f32_to_bf16_rne(float f) {
    uint32 u = __float_as_uint(f);
    return (u + 0x7fffu + ((u >> 16) & 1u)) >> 16;
}
static __device__ __forceinline__ float bf16_lo(uint32 v) {   // feats 2*lane
    return __uint_as_float(v << 16);
}
static __device__ __forceinline__ float bf16_hi(uint32 v) {   // feats 2*lane+1
    return __uint_as_float(v & 0xffff0000u);
}

// ---------------------------------------------------------------------------
// hs[r][c] = dis[r] * sum_k A[gather(r)][k] * W[k][c]      (A is N x 128, f32)
// Output is PACKED bf16 (uint32 = 2 feats) -> row = 256B (halves gather bytes).
// Register blocking: 4 rows x 8 cols per thread; 64 rows per 256-thread block.
// ---------------------------------------------------------------------------
__global__ __launch_bounds__(256)
void gemm_scale_kernel(const float* __restrict__ A, const int* __restrict__ gather,
                       const float* __restrict__ W0, const float* __restrict__ W1b,
                       int wstride, const float* __restrict__ dis,
                       uint32* __restrict__ out, int n_rows) {
    int grp = threadIdx.x >> 4;            // 0..15
    int c8  = (threadIdx.x & 15) * 8;      // col block
    int r0  = blockIdx.x * 64 + grp * 4;   // first of 4 rows
    if (r0 >= n_rows) return;

    const float* wb = (c8 < 64) ? (W0 + c8) : (W1b + (c8 - 64));

    const float* ap[4];
    #pragma unroll
    for (int i = 0; i < 4; i++) {
        int r = r0 + i;
        if (r > n_rows - 1) r = n_rows - 1;
        int ra = gather ? gather[r] : r;
        ap[i] = A + (size_t)ra * 128;
    }

    float acc[4][8];
    #pragma unroll
    for (int i = 0; i < 4; i++)
        #pragma unroll
        for (int j = 0; j < 8; j++) acc[i][j] = 0.f;

    for (int k = 0; k < 128; k += 4) {
        float4 av[4];
        #pragma unroll
        for (int i = 0; i < 4; i++) av[i] = *(const float4*)(ap[i] + k);

        const float* w = wb + (size_t)k * wstride;
        #pragma unroll
        for (int kk = 0; kk < 4; kk++) {
            float4 w0 = *(const float4*)(w);
            float4 w1 = *(const float4*)(w + 4);
            #pragma unroll
            for (int i = 0; i < 4; i++) {
                float s = (kk == 0) ? av[i].x : (kk == 1) ? av[i].y
                        : (kk == 2) ? av[i].z : av[i].w;
                acc[i][0] = fmaf(s, w0.x, acc[i][0]);
                acc[i][1] = fmaf(s, w0.y, acc[i][1]);
                acc[i][2] = fmaf(s, w0.z, acc[i][2]);
                acc[i][3] = fmaf(s, w0.w, acc[i][3]);
                acc[i][4] = fmaf(s, w1.x, acc[i][4]);
                acc[i][5] = fmaf(s, w1.y, acc[i][5]);
                acc[i][6] = fmaf(s, w1.z, acc[i][6]);
                acc[i][7] = fmaf(s, w1.w, acc[i][7]);
            }
            w += wstride;
        }
    }

    #pragma unroll
    for (int i = 0; i < 4; i++) {
        int r = r0 + i;
        if (r < n_rows) {
            float d = dis[r];
            uint4 pk;
            pk.x = f32_to_bf16_rne(d * acc[i][0]) | (f32_to_bf16_rne(d * acc[i][1]) << 16);
            pk.y = f32_to_bf16_rne(d * acc[i][2]) | (f32_to_bf16_rne(d * acc[i][3]) << 16);
            pk.z = f32_to_bf16_rne(d * acc[i][4]) | (f32_to_bf16_rne(d * acc[i][5]) << 16);
            pk.w = f32_to_bf16_rne(d * acc[i][6]) | (f32_to_bf16_rne(d * acc[i][7]) << 16);
            *(uint4*)(out + (size_t)r * 64 + (c8 >> 1)) = pk;
        }
    }
}

// ---------------------------------------------------------------------------
// Aggregation: one wave per target node v over bf16-packed hs rows (256B).
// Lane l owns feats (2l, 2l+1) as one uint32; accumulate in f32; unroll 8.
// ---------------------------------------------------------------------------
__global__ __launch_bounds__(256)
void agg_relu_kernel(const uint32* __restrict__ hs, const uint32* __restrict__ offs,
                     const uint32* __restrict__ csr, const float* __restrict__ dis,
                     const float* __restrict__ bias, float* __restrict__ out, int n_nodes) {
    int wid = (blockIdx.x * 256 + (int)threadIdx.x) >> 6;
    int lane = threadIdx.x & 63;
    if (wid >= n_nodes) return;

    uint32 sv = hs[(size_t)wid * 64 + lane];        // self-loop term
    float ax = bf16_lo(sv), ay = bf16_hi(sv);
    int beg = (int)offs[wid], end = (int)offs[wid + 1];

    int j = beg;
    for (; j + 8 <= end; j += 8) {
        uint32 e0 = csr[j],     e1 = csr[j + 1], e2 = csr[j + 2], e3 = csr[j + 3];
        uint32 e4 = csr[j + 4], e5 = csr[j + 5], e6 = csr[j + 6], e7 = csr[j + 7];
        uint32 v0 = hs[(size_t)e0 * 64 + lane];
        uint32 v1 = hs[(size_t)e1 * 64 + lane];
        uint32 v2 = hs[(size_t)e2 * 64 + lane];
        uint32 v3 = hs[(size_t)e3 * 64 + lane];
        uint32 v4 = hs[(size_t)e4 * 64 + lane];
        uint32 v5 = hs[(size_t)e5 * 64 + lane];
        uint32 v6 = hs[(size_t)e6 * 64 + lane];
        uint32 v7 = hs[(size_t)e7 * 64 + lane];
        float sx = ((bf16_lo(v0) + bf16_lo(v1)) + (bf16_lo(v2) + bf16_lo(v3)))
                 + ((bf16_lo(v4) + bf16_lo(v5)) + (bf16_lo(v6) + bf16_lo(v7)));
        float sy = ((bf16_hi(v0) + bf16_hi(v1)) + (bf16_hi(v2) + bf16_hi(v3)))
                 + ((bf16_hi(v4) + bf16_hi(v5)) + (bf16_hi(v6) + bf16_hi(v7)));
        ax += sx; ay += sy;
    }
    for (; j < end; ++j) {
        uint32 v = hs[(size_t)csr[j] * 64 + lane];
        ax += bf16_lo(v); ay += bf16_hi(v);
    }

    float d = dis[wid];
    float2 b = ((const float2*)bias)[lane];
    float2 o;
    o.x = fmaxf(fmaf(d, ax, b.x), 0.f);
    o.y = fmaxf(fmaf(d, ay, b.y), 0.f);
    ((float2*)out)[(size_t)wid * 64 + lane] = o;
}

// Layer 2: feats 0..63 -> mu (+b_mu), 64..127 -> logvar (+b_logvar), no relu.
__global__ __launch_bounds__(256)
void agg_out_kernel(const uint32* __restrict__ hs, const uint32* __restrict__ offs,
                    const uint32* __restrict__ csr, const float* __restrict__ dis,
                    const float* __restrict__ bmu, const float* __restrict__ blv,
                    float* __restrict__ out_mu, float* __restrict__ out_lv, int n_nodes) {
    int wid = (blockIdx.x * 256 + (int)threadIdx.x) >> 6;
    int lane = threadIdx.x & 63;
    if (wid >= n_nodes) return;

    uint32 sv = hs[(size_t)wid * 64 + lane];
    float ax = bf16_lo(sv), ay = bf16_hi(sv);
    int beg = (int)offs[wid], end = (int)offs[wid + 1];

    int j = beg;
    for (; j + 8 <= end; j += 8) {
        uint32 e0 = csr[j],     e1 = csr[j + 1], e2 = csr[j + 2], e3 = csr[j + 3];
        uint32 e4 = csr[j + 4], e5 = csr[j + 5], e6 = csr[j + 6], e7 = csr[j + 7];
        uint32 v0 = hs[(size_t)e0 * 64 + lane];
        uint32 v1 = hs[(size_t)e1 * 64 + lane];
        uint32 v2 = hs[(size_t)e2 * 64 + lane];
        uint32 v3 = hs[(size_t)e3 * 64 + lane];
        uint32 v4 = hs[(size_t)e4 * 64 + lane];
        uint32 v5 = hs[(size_t)e5 * 64 + lane];
        uint32 v6 = hs[(size_t)e6 * 64 + lane];
        uint32 v7 = hs[(size_t)e7 * 64 + lane];
        float sx = ((bf16_lo(v0) + bf16_lo(v1)) + (bf16_lo(v2) + bf16_lo(v3)))
                 + ((bf16_lo(v4) + bf16_lo(v5)) + (bf16_lo(v6) + bf16_lo(v7)));
        float sy = ((bf16_hi(v0) + bf16_hi(v1)) + (bf16_hi(v2) + bf16_hi(v3)))
                 + ((bf16_hi(v4) + bf16_hi(v5)) + (bf16_hi(v6) + bf16_hi(v7)));
        ax += sx; ay += sy;
    }
    for (; j < end; ++j) {
        uint32 v = hs[(size_t)csr[j] * 64 + lane];
        ax += bf16_lo(v); ay += bf16_hi(v);
    }

    float d = dis[wid];
    if (lane < 32) {
        float2 b = ((const float2*)bmu)[lane];
        float2 o = make_float2(fmaf(d, ax, b.x), fmaf(d, ay, b.y));
        ((float2*)out_mu)[(size_t)wid * 32 + lane] = o;
    } else {
        int l2 = lane - 32;
        float2 b = ((const float2*)blv)[l2];
        float2 o = make_float2(fmaf(d, ax, b.x), fmaf(d, ay, b.y));
        ((float2*)out_lv)[(size_t)wid * 32 + l2] = o;
    }
}

// ---------------------------------------------------------------------------

extern "C" void kernel_launch(void* const* d_in, const int* in_sizes, int n_in,
                              void* d_out, int out_size, void* d_ws, size_t ws_size,
                              hipStream_t stream) {
    const int*   x   = (const int*)d_in[0];
    const int*   ei  = (const int*)d_in[1];
    const float* emb = (const float*)d_in[2];
    const float* W1  = (const float*)d_in[3];
    const float* b1  = (const float*)d_in[4];
    const float* Wmu = (const float*)d_in[5];
    const float* bmu = (const float*)d_in[6];
    const float* Wlv = (const float*)d_in[7];
    const float* blv = (const float*)d_in[8];

    int n_nodes = in_sizes[0];
    int n_edges = in_sizes[1] / 2;
    const int* row = ei;              // source nodes
    const int* col = ei + n_edges;    // target nodes (aggregation index)

    // Workspace carve-out (all 256B-aligned).
    char* wp = (char*)d_ws;
    auto carve = [&wp](size_t bytes) -> char* {
        char* p = wp;
        wp += (bytes + 255) & ~(size_t)255;
        return p;
    };
    int nb = (n_nodes + 255) / 256;   // scan blocks (196 for 50k, <= 1024)

    uint32* cnt     = (uint32*)carve((size_t)n_nodes * 4);
    uint32* cursor  = (uint32*)carve((size_t)n_nodes * 4);
    uint32* offs    = (uint32*)carve(((size_t)n_nodes + 1) * 4);
    uint32* partial = (uint32*)carve((size_t)n_nodes * 4);
    uint32* bsums   = (uint32*)carve((size_t)nb * 4);
    uint32* boffs   = (uint32*)carve((size_t)nb * 4);
    float*  dis     = (float*) carve((size_t)n_nodes * 4);
    uint32* csr     = (uint32*)carve((size_t)n_edges * 4);
    uint32* bufA    = (uint32*)carve((size_t)n_nodes * 64 * 4);    // hs, packed bf16
    float*  bufB    = (float*) carve((size_t)n_nodes * 128 * 4);   // h1, f32

    int gb_e = (n_edges + 255) / 256;

    hipLaunchKernelGGL(zero_cnt_kernel, dim3(nb), dim3(256), 0, stream, cnt, n_nodes);
    hipLaunchKernelGGL(count_kernel, dim3(gb_e), dim3(256), 0, stream, col, n_edges, cnt);
    hipLaunchKernelGGL(scan_blk_kernel, dim3(nb), dim3(256), 0, stream, cnt, partial, bsums, n_nodes);
    hipLaunchKernelGGL(scan_sums_kernel, dim3(1), dim3(1024), 0, stream, bsums, boffs, nb);
    hipLaunchKernelGGL(scan_add_kernel, dim3(nb), dim3(256), 0, stream,
                       partial, boffs, cnt, offs, dis, cursor, n_nodes, n_edges);
    hipLaunchKernelGGL(fill_kernel, dim3(gb_e), dim3(256), 0, stream, row, col, n_edges, offs, cursor, csr);

    int gemm_blocks = (n_nodes + 63) / 64;
    int agg_blocks  = (n_nodes + 3) / 4;

    // Layer 1: hs = bf16( (emb[x] @ W1) * dis ) ; h1 = relu(dis * (agg + self) + b1)
    hipLaunchKernelGGL(gemm_scale_kernel, dim3(gemm_blocks), dim3(256), 0, stream,
                       emb, x, W1, W1 + 64, 128, dis, bufA, n_nodes);
    hipLaunchKernelGGL(agg_relu_kernel, dim3(agg_blocks), dim3(256), 0, stream,
                       bufA, offs, csr, dis, b1, bufB, n_nodes);

    // Layer 2 (mu and logvar fused into one 128-wide pass)
    hipLaunchKernelGGL(gemm_scale_kernel, dim3(gemm_blocks), dim3(256), 0, stream,
                       bufB, (const int*)nullptr, Wmu, Wlv, 64, dis, bufA, n_nodes);

    float* out_mu = (float*)d_out;
    float* out_lv = out_mu + (size_t)n_nodes * 64;
    hipLaunchKernelGGL(agg_out_kernel, dim3(agg_blocks), dim3(256), 0, stream,
                       bufA, offs, csr, dis, bmu, blv, out_mu, out_lv, n_nodes);
}

// Round 8
// 466.299 us; speedup vs baseline: 1.6049x; 1.0632x over previous
//
#include <hip/hip_runtime.h>
#include <hip/hip_bf16.h>

typedef unsigned int uint32;

// ---------------------------------------------------------------------------
// Graph preprocessing: degree count -> hierarchical exclusive scan -> CSR fill
// ---------------------------------------------------------------------------

__global__ __launch_bounds__(256)
void zero_cnt_kernel(uint32* __restrict__ cnt, int n) {
    int i = blockIdx.x * 256 + threadIdx.x;
    if (i < n) cnt[i] = 0u;
}

__global__ __launch_bounds__(256)
void count_kernel(const int* __restrict__ col, int n_edges, uint32* __restrict__ cnt) {
    int e = blockIdx.x * 256 + threadIdx.x;
    if (e < n_edges) atomicAdd(&cnt[col[e]], 1u);
}

// Stage 1: per-block (256 elems) exclusive scan + per-block sum.
__global__ __launch_bounds__(256)
void scan_blk_kernel(const uint32* __restrict__ cnt, uint32* __restrict__ partial,
                     uint32* __restrict__ blk_sums, int n) {
    __shared__ uint32 sh[256];
    int i = blockIdx.x * 256 + (int)threadIdx.x;
    uint32 v = (i < n) ? cnt[i] : 0u;
    sh[threadIdx.x] = v;
    __syncthreads();
    for (int off = 1; off < 256; off <<= 1) {
        uint32 t = (threadIdx.x >= (unsigned)off) ? sh[threadIdx.x - off] : 0u;
        __syncthreads();
        sh[threadIdx.x] += t;
        __syncthreads();
    }
    if (i < n) partial[i] = sh[threadIdx.x] - v;      // exclusive within block
    if (threadIdx.x == 255) blk_sums[blockIdx.x] = sh[255];
}

// Stage 2: one block scans the block sums (nb <= 1024).
__global__ __launch_bounds__(1024)
void scan_sums_kernel(const uint32* __restrict__ blk_sums, uint32* __restrict__ blk_offs, int nb) {
    __shared__ uint32 sh[1024];
    uint32 v = ((int)threadIdx.x < nb) ? blk_sums[threadIdx.x] : 0u;
    sh[threadIdx.x] = v;
    __syncthreads();
    for (int off = 1; off < 1024; off <<= 1) {
        uint32 t = (threadIdx.x >= (unsigned)off) ? sh[threadIdx.x - off] : 0u;
        __syncthreads();
        sh[threadIdx.x] += t;
        __syncthreads();
    }
    if ((int)threadIdx.x < nb) blk_offs[threadIdx.x] = sh[threadIdx.x] - v;
}

// Stage 3: offs = partial + blk_offs; fused dis = rsqrt(deg+1) and cursor = 0.
__global__ __launch_bounds__(256)
void scan_add_kernel(const uint32* __restrict__ partial, const uint32* __restrict__ blk_offs,
                     const uint32* __restrict__ cnt, uint32* __restrict__ offs,
                     float* __restrict__ dis, uint32* __restrict__ cursor,
                     int n, int n_edges) {
    int i = blockIdx.x * 256 + (int)threadIdx.x;
    if (i < n) {
        offs[i] = partial[i] + blk_offs[blockIdx.x];
        dis[i] = rsqrtf((float)(cnt[i] + 1u));   // self-loop => deg >= 1
        cursor[i] = 0u;
    }
    if (i == 0) offs[n] = (uint32)n_edges;       // sum of cnt == n_edges
}

// ---------------------------------------------------------------------------
// bf16 helpers (RNE, deterministic)
// ---------------------------------------------------------------------------
static __device__ __forceinline__ uint32 f32_to_bf16_rne(float f) {
    uint32 u = __float_as_uint(f);
    return (u + 0x7fffu + ((u >> 16) & 1u)) >> 16;
}
static __device__ __forceinline__ float bf16_lo(uint32 v) {   // feats 2*lane
    return __uint_as_float(v << 16);
}
static __device__ __forceinline__ float bf16_hi(uint32 v) {   // feats 2*lane+1
    return __uint_as_float(v & 0xffff0000u);
}

// ---------------------------------------------------------------------------
// GEMM body: hs[r][c] = sum_k A[gather(r)][k] * W[k][c]   (UNscaled; dis is
// applied per-edge in the agg kernels). Packed-bf16 output (row = 256B).
// 4 rows x 8 cols per thread; 64 rows per 256-thread block.
// ---------------------------------------------------------------------------
static __device__ __forceinline__
void gemm_body(int gbid, const float* __restrict__ A, const int* __restrict__ gather,
               const float* __restrict__ W0, const float* __restrict__ W1b,
               int wstride, uint32* __restrict__ out, int n_rows) {
    int grp = threadIdx.x >> 4;            // 0..15
    int c8  = (threadIdx.x & 15) * 8;      // col block
    int r0  = gbid * 64 + grp * 4;         // first of 4 rows
    if (r0 >= n_rows) return;

    const float* wb = (c8 < 64) ? (W0 + c8) : (W1b + (c8 - 64));

    const float* ap[4];
    #pragma unroll
    for (int i = 0; i < 4; i++) {
        int r = r0 + i;
        if (r > n_rows - 1) r = n_rows - 1;
        int ra = gather ? gather[r] : r;
        ap[i] = A + (size_t)ra * 128;
    }

    float acc[4][8];
    #pragma unroll
    for (int i = 0; i < 4; i++)
        #pragma unroll
        for (int j = 0; j < 8; j++) acc[i][j] = 0.f;

    for (int k = 0; k < 128; k += 4) {
        float4 av[4];
        #pragma unroll
        for (int i = 0; i < 4; i++) av[i] = *(const float4*)(ap[i] + k);

        const float* w = wb + (size_t)k * wstride;
        #pragma unroll
        for (int kk = 0; kk < 4; kk++) {
            float4 w0 = *(const float4*)(w);
            float4 w1 = *(const float4*)(w + 4);
            #pragma unroll
            for (int i = 0; i < 4; i++) {
                float s = (kk == 0) ? av[i].x : (kk == 1) ? av[i].y
                        : (kk == 2) ? av[i].z : av[i].w;
                acc[i][0] = fmaf(s, w0.x, acc[i][0]);
                acc[i][1] = fmaf(s, w0.y, acc[i][1]);
                acc[i][2] = fmaf(s, w0.z, acc[i][2]);
                acc[i][3] = fmaf(s, w0.w, acc[i][3]);
                acc[i][4] = fmaf(s, w1.x, acc[i][4]);
                acc[i][5] = fmaf(s, w1.y, acc[i][5]);
                acc[i][6] = fmaf(s, w1.z, acc[i][6]);
                acc[i][7] = fmaf(s, w1.w, acc[i][7]);
            }
            w += wstride;
        }
    }

    #pragma unroll
    for (int i = 0; i < 4; i++) {
        int r = r0 + i;
        if (r < n_rows) {
            uint4 pk;
            pk.x = f32_to_bf16_rne(acc[i][0]) | (f32_to_bf16_rne(acc[i][1]) << 16);
            pk.y = f32_to_bf16_rne(acc[i][2]) | (f32_to_bf16_rne(acc[i][3]) << 16);
            pk.z = f32_to_bf16_rne(acc[i][4]) | (f32_to_bf16_rne(acc[i][5]) << 16);
            pk.w = f32_to_bf16_rne(acc[i][6]) | (f32_to_bf16_rne(acc[i][7]) << 16);
            *(uint4*)(out + (size_t)r * 64 + (c8 >> 1)) = pk;
        }
    }
}

// ---------------------------------------------------------------------------
// Fused: CSR fill (latency-bound scatter) + layer-1 GEMM (VALU-bound).
// Independent work; role-interleaved blocks (every 9th = gemm) so both wave
// populations are co-resident and the CU overlaps VALU with scatter latency.
// ---------------------------------------------------------------------------
__global__ __launch_bounds__(256)
void fill_gemm_kernel(const int* __restrict__ row, const int* __restrict__ col,
                      int n_edges, const uint32* __restrict__ offs,
                      uint32* __restrict__ cursor, uint32* __restrict__ csr,
                      const float* __restrict__ A, const int* __restrict__ gather,
                      const float* __restrict__ W0, const float* __restrict__ W1b,
                      int wstride, uint32* __restrict__ out, int n_rows,
                      int n_gemm_blocks) {
    int bid = blockIdx.x;
    int q = bid / 9, r = bid % 9;
    bool is_gemm = (r == 0) && (q < n_gemm_blocks);
    if (is_gemm) {
        gemm_body(q, A, gather, W0, W1b, wstride, out, n_rows);
    } else {
        int before = q + (r ? 1 : 0);
        if (before > n_gemm_blocks) before = n_gemm_blocks;
        int fid = bid - before;
        int e = fid * 256 + (int)threadIdx.x;
        if (e < n_edges) {
            int c = col[e];
            uint32 p = offs[c] + atomicAdd(&cursor[c], 1u);
            csr[p] = (uint32)row[e];
        }
    }
}

// Standalone gemm (layer 2)
__global__ __launch_bounds__(256)
void gemm_kernel(const float* __restrict__ A,
                 const float* __restrict__ W0, const float* __restrict__ W1b,
                 int wstride, uint32* __restrict__ out, int n_rows) {
    gemm_body(blockIdx.x, A, (const int*)nullptr, W0, W1b, wstride, out, n_rows);
}

// ---------------------------------------------------------------------------
// Aggregation: one wave per target node v over bf16-packed UNscaled hs rows.
//   acc = dis[v]*h[v] + sum_e dis[row_e]*h[row_e]   (dis[r]: wave-broadcast load)
//   out = dis[v]*acc + b
// Lane l owns feats (2l, 2l+1) as one uint32; accumulate in f32; unroll 8.
// ---------------------------------------------------------------------------
__global__ __launch_bounds__(256)
void agg_relu_kernel(const uint32* __restrict__ hs, const uint32* __restrict__ offs,
                     const uint32* __restrict__ csr, const float* __restrict__ dis,
                     const float* __restrict__ bias, float* __restrict__ out, int n_nodes) {
    int wid = (blockIdx.x * 256 + (int)threadIdx.x) >> 6;
    int lane = threadIdx.x & 63;
    if (wid >= n_nodes) return;

    float dv = dis[wid];
    uint32 sv = hs[(size_t)wid * 64 + lane];        // self-loop term
    float ax = dv * bf16_lo(sv), ay = dv * bf16_hi(sv);
    int beg = (int)offs[wid], end = (int)offs[wid + 1];

    int j = beg;
    for (; j + 8 <= end; j += 8) {
        uint32 e0 = csr[j],     e1 = csr[j + 1], e2 = csr[j + 2], e3 = csr[j + 3];
        uint32 e4 = csr[j + 4], e5 = csr[j + 5], e6 = csr[j + 6], e7 = csr[j + 7];
        float d0 = dis[e0], d1 = dis[e1], d2 = dis[e2], d3 = dis[e3];
        float d4 = dis[e4], d5 = dis[e5], d6 = dis[e6], d7 = dis[e7];
        uint32 v0 = hs[(size_t)e0 * 64 + lane];
        uint32 v1 = hs[(size_t)e1 * 64 + lane];
        uint32 v2 = hs[(size_t)e2 * 64 + lane];
        uint32 v3 = hs[(size_t)e3 * 64 + lane];
        uint32 v4 = hs[(size_t)e4 * 64 + lane];
        uint32 v5 = hs[(size_t)e5 * 64 + lane];
        uint32 v6 = hs[(size_t)e6 * 64 + lane];
        uint32 v7 = hs[(size_t)e7 * 64 + lane];
        ax = fmaf(d0, bf16_lo(v0), ax); ay = fmaf(d0, bf16_hi(v0), ay);
        ax = fmaf(d1, bf16_lo(v1), ax); ay = fmaf(d1, bf16_hi(v1), ay);
        ax = fmaf(d2, bf16_lo(v2), ax); ay = fmaf(d2, bf16_hi(v2), ay);
        ax = fmaf(d3, bf16_lo(v3), ax); ay = fmaf(d3, bf16_hi(v3), ay);
        ax = fmaf(d4, bf16_lo(v4), ax); ay = fmaf(d4, bf16_hi(v4), ay);
        ax = fmaf(d5, bf16_lo(v5), ax); ay = fmaf(d5, bf16_hi(v5), ay);
        ax = fmaf(d6, bf16_lo(v6), ax); ay = fmaf(d6, bf16_hi(v6), ay);
        ax = fmaf(d7, bf16_lo(v7), ax); ay = fmaf(d7, bf16_hi(v7), ay);
    }
    for (; j < end; ++j) {
        uint32 e = csr[j];
        float d = dis[e];
        uint32 v = hs[(size_t)e * 64 + lane];
        ax = fmaf(d, bf16_lo(v), ax); ay = fmaf(d, bf16_hi(v), ay);
    }

    float2 b = ((const float2*)bias)[lane];
    float2 o;
    o.x = fmaxf(fmaf(dv, ax, b.x), 0.f);
    o.y = fmaxf(fmaf(dv, ay, b.y), 0.f);
    ((float2*)out)[(size_t)wid * 64 + lane] = o;
}

// Layer 2: feats 0..63 -> mu (+b_mu), 64..127 -> logvar (+b_logvar), no relu.
__global__ __launch_bounds__(256)
void agg_out_kernel(const uint32* __restrict__ hs, const uint32* __restrict__ offs,
                    const uint32* __restrict__ csr, const float* __restrict__ dis,
                    const float* __restrict__ bmu, const float* __restrict__ blv,
                    float* __restrict__ out_mu, float* __restrict__ out_lv, int n_nodes) {
    int wid = (blockIdx.x * 256 + (int)threadIdx.x) >> 6;
    int lane = threadIdx.x & 63;
    if (wid >= n_nodes) return;

    float dv = dis[wid];
    uint32 sv = hs[(size_t)wid * 64 + lane];
    float ax = dv * bf16_lo(sv), ay = dv * bf16_hi(sv);
    int beg = (int)offs[wid], end = (int)offs[wid + 1];

    int j = beg;
    for (; j + 8 <= end; j += 8) {
        uint32 e0 = csr[j],     e1 = csr[j + 1], e2 = csr[j + 2], e3 = csr[j + 3];
        uint32 e4 = csr[j + 4], e5 = csr[j + 5], e6 = csr[j + 6], e7 = csr[j + 7];
        float d0 = dis[e0], d1 = dis[e1], d2 = dis[e2], d3 = dis[e3];
        float d4 = dis[e4], d5 = dis[e5], d6 = dis[e6], d7 = dis[e7];
        uint32 v0 = hs[(size_t)e0 * 64 + lane];
        uint32 v1 = hs[(size_t)e1 * 64 + lane];
        uint32 v2 = hs[(size_t)e2 * 64 + lane];
        uint32 v3 = hs[(size_t)e3 * 64 + lane];
        uint32 v4 = hs[(size_t)e4 * 64 + lane];
        uint32 v5 = hs[(size_t)e5 * 64 + lane];
        uint32 v6 = hs[(size_t)e6 * 64 + lane];
        uint32 v7 = hs[(size_t)e7 * 64 + lane];
        ax = fmaf(d0, bf16_lo(v0), ax); ay = fmaf(d0, bf16_hi(v0), ay);
        ax = fmaf(d1, bf16_lo(v1), ax); ay = fmaf(d1, bf16_hi(v1), ay);
        ax = fmaf(d2, bf16_lo(v2), ax); ay = fmaf(d2, bf16_hi(v2), ay);
        ax = fmaf(d3, bf16_lo(v3), ax); ay = fmaf(d3, bf16_hi(v3), ay);
        ax = fmaf(d4, bf16_lo(v4), ax); ay = fmaf(d4, bf16_hi(v4), ay);
        ax = fmaf(d5, bf16_lo(v5), ax); ay = fmaf(d5, bf16_hi(v5), ay);
        ax = fmaf(d6, bf16_lo(v6), ax); ay = fmaf(d6, bf16_hi(v6), ay);
        ax = fmaf(d7, bf16_lo(v7), ax); ay = fmaf(d7, bf16_hi(v7), ay);
    }
    for (; j < end; ++j) {
        uint32 e = csr[j];
        float d = dis[e];
        uint32 v = hs[(size_t)e * 64 + lane];
        ax = fmaf(d, bf16_lo(v), ax); ay = fmaf(d, bf16_hi(v), ay);
    }

    if (lane < 32) {
        float2 b = ((const float2*)bmu)[lane];
        float2 o = make_float2(fmaf(dv, ax, b.x), fmaf(dv, ay, b.y));
        ((float2*)out_mu)[(size_t)wid * 32 + lane] = o;
    } else {
        int l2 = lane - 32;
        float2 b = ((const float2*)blv)[l2];
        float2 o = make_float2(fmaf(dv, ax, b.x), fmaf(dv, ay, b.y));
        ((float2*)out_lv)[(size_t)wid * 32 + l2] = o;
    }
}

// ---------------------------------------------------------------------------

extern "C" void kernel_launch(void* const* d_in, const int* in_sizes, int n_in,
                              void* d_out, int out_size, void* d_ws, size_t ws_size,
                              hipStream_t stream) {
    const int*   x   = (const int*)d_in[0];
    const int*   ei  = (const int*)d_in[1];
    const float* emb = (const float*)d_in[2];
    const float* W1  = (const float*)d_in[3];
    const float* b1  = (const float*)d_in[4];
    const float* Wmu = (const float*)d_in[5];
    const float* bmu = (const float*)d_in[6];
    const float* Wlv = (const float*)d_in[7];
    const float* blv = (const float*)d_in[8];

    int n_nodes = in_sizes[0];
    int n_edges = in_sizes[1] / 2;
    const int* row = ei;              // source nodes
    const int* col = ei + n_edges;    // target nodes (aggregation index)

    // Workspace carve-out (all 256B-aligned).
    char* wp = (char*)d_ws;
    auto carve = [&wp](size_t bytes) -> char* {
        char* p = wp;
        wp += (bytes + 255) & ~(size_t)255;
        return p;
    };
    int nb = (n_nodes + 255) / 256;   // scan blocks (196 for 50k, <= 1024)

    uint32* cnt     = (uint32*)carve((size_t)n_nodes * 4);
    uint32* cursor  = (uint32*)carve((size_t)n_nodes * 4);
    uint32* offs    = (uint32*)carve(((size_t)n_nodes + 1) * 4);
    uint32* partial = (uint32*)carve((size_t)n_nodes * 4);
    uint32* bsums   = (uint32*)carve((size_t)nb * 4);
    uint32* boffs   = (uint32*)carve((size_t)nb * 4);
    float*  dis     = (float*) carve((size_t)n_nodes * 4);
    uint32* csr     = (uint32*)carve((size_t)n_edges * 4);
    uint32* bufA    = (uint32*)carve((size_t)n_nodes * 64 * 4);    // hs, packed bf16
    float*  bufB    = (float*) carve((size_t)n_nodes * 128 * 4);   // h1, f32

    int gb_e = (n_edges + 255) / 256;            // fill blocks (6250)
    int gemm_blocks = (n_nodes + 63) / 64;       // 782
    int agg_blocks  = (n_nodes + 3) / 4;

    hipLaunchKernelGGL(zero_cnt_kernel, dim3(nb), dim3(256), 0, stream, cnt, n_nodes);
    hipLaunchKernelGGL(count_kernel, dim3(gb_e), dim3(256), 0, stream, col, n_edges, cnt);
    hipLaunchKernelGGL(scan_blk_kernel, dim3(nb), dim3(256), 0, stream, cnt, partial, bsums, n_nodes);
    hipLaunchKernelGGL(scan_sums_kernel, dim3(1), dim3(1024), 0, stream, bsums, boffs, nb);
    hipLaunchKernelGGL(scan_add_kernel, dim3(nb), dim3(256), 0, stream,
                       partial, boffs, cnt, offs, dis, cursor, n_nodes, n_edges);

    // Fused: CSR fill + layer-1 GEMM (hs = bf16(emb[x] @ W1), unscaled)
    hipLaunchKernelGGL(fill_gemm_kernel, dim3(gb_e + gemm_blocks), dim3(256), 0, stream,
                       row, col, n_edges, offs, cursor, csr,
                       emb, x, W1, W1 + 64, 128, bufA, n_nodes, gemm_blocks);

    hipLaunchKernelGGL(agg_relu_kernel, dim3(agg_blocks), dim3(256), 0, stream,
                       bufA, offs, csr, dis, b1, bufB, n_nodes);

    // Layer 2 (mu and logvar fused into one 128-wide pass)
    hipLaunchKernelGGL(gemm_kernel, dim3(gemm_blocks), dim3(256), 0, stream,
                       bufB, Wmu, Wlv, 64, bufA, n_nodes);

    float* out_mu = (float*)d_out;
    float* out_lv = out_mu + (size_t)n_nodes * 64;
    hipLaunchKernelGGL(agg_out_kernel, dim3(agg_blocks), dim3(256), 0, stream,
                       bufA, offs, csr, dis, bmu, blv, out_mu, out_lv, n_nodes);
}

// Round 13
// 453.444 us; speedup vs baseline: 1.6504x; 1.0284x over previous
//
#include <hip/hip_runtime.h>
#include <hip/hip_bf16.h>

typedef unsigned int uint32;

// ---------------------------------------------------------------------------
// Graph preprocessing: degree count -> hierarchical exclusive scan -> CSR fill
// ---------------------------------------------------------------------------

__global__ __launch_bounds__(256)
void count_kernel(const int* __restrict__ col, int n_edges, uint32* __restrict__ cnt) {
    int e = blockIdx.x * 256 + threadIdx.x;
    if (e < n_edges) atomicAdd(&cnt[col[e]], 1u);
}

// Stage 1: per-block (256 elems) exclusive scan + per-block sum.
__global__ __launch_bounds__(256)
void scan_blk_kernel(const uint32* __restrict__ cnt, uint32* __restrict__ partial,
                     uint32* __restrict__ blk_sums, int n) {
    __shared__ uint32 sh[256];
    int i = blockIdx.x * 256 + (int)threadIdx.x;
    uint32 v = (i < n) ? cnt[i] : 0u;
    sh[threadIdx.x] = v;
    __syncthreads();
    for (int off = 1; off < 256; off <<= 1) {
        uint32 t = (threadIdx.x >= (unsigned)off) ? sh[threadIdx.x - off] : 0u;
        __syncthreads();
        sh[threadIdx.x] += t;
        __syncthreads();
    }
    if (i < n) partial[i] = sh[threadIdx.x] - v;      // exclusive within block
    if (threadIdx.x == 255) blk_sums[blockIdx.x] = sh[255];
}

// Stage 2: one block scans the block sums (nb <= 1024).
__global__ __launch_bounds__(1024)
void scan_sums_kernel(const uint32* __restrict__ blk_sums, uint32* __restrict__ blk_offs, int nb) {
    __shared__ uint32 sh[1024];
    uint32 v = ((int)threadIdx.x < nb) ? blk_sums[threadIdx.x] : 0u;
    sh[threadIdx.x] = v;
    __syncthreads();
    for (int off = 1; off < 1024; off <<= 1) {
        uint32 t = (threadIdx.x >= (unsigned)off) ? sh[threadIdx.x - off] : 0u;
        __syncthreads();
        sh[threadIdx.x] += t;
        __syncthreads();
    }
    if ((int)threadIdx.x < nb) blk_offs[threadIdx.x] = sh[threadIdx.x] - v;
}

// Stage 3: offs = partial + blk_offs; fused dis = rsqrt(deg+1) and cursor = 0.
__global__ __launch_bounds__(256)
void scan_add_kernel(const uint32* __restrict__ partial, const uint32* __restrict__ blk_offs,
                     const uint32* __restrict__ cnt, uint32* __restrict__ offs,
                     float* __restrict__ dis, uint32* __restrict__ cursor,
                     int n, int n_edges) {
    int i = blockIdx.x * 256 + (int)threadIdx.x;
    if (i < n) {
        offs[i] = partial[i] + blk_offs[blockIdx.x];
        dis[i] = rsqrtf((float)(cnt[i] + 1u));   // self-loop => deg >= 1
        cursor[i] = 0u;
    }
    if (i == 0) offs[n] = (uint32)n_edges;       // sum of cnt == n_edges
}

// ---------------------------------------------------------------------------
// bf16 helpers (RNE, deterministic)
// ---------------------------------------------------------------------------
static __device__ __forceinline__ uint32 f32_to_bf16_rne(float f) {
    uint32 u = __float_as_uint(f);
    return (u + 0x7fffu + ((u >> 16) & 1u)) >> 16;
}
static __device__ __forceinline__ float bf16_lo(uint32 v) {   // feats 2*lane
    return __uint_as_float(v << 16);
}
static __device__ __forceinline__ float bf16_hi(uint32 v) {   // feats 2*lane+1
    return __uint_as_float(v & 0xffff0000u);
}

// ---------------------------------------------------------------------------
// GEMM body: hs[r][c] = sum_k A[gather(r)][k] * W[k][c]   (UNscaled; dis is
// applied per-edge in the agg kernels). Packed-bf16 output (row = 256B).
// 4 rows x 8 cols per thread; 64 rows per 256-thread block.
// ---------------------------------------------------------------------------
static __device__ __forceinline__
void gemm_body(int gbid, const float* __restrict__ A, const int* __restrict__ gather,
               const float* __restrict__ W0, const float* __restrict__ W1b,
               int wstride, uint32* __restrict__ out, int n_rows) {
    int grp = threadIdx.x >> 4;            // 0..15
    int c8  = (threadIdx.x & 15) * 8;      // col block
    int r0  = gbid * 64 + grp * 4;         // first of 4 rows
    if (r0 >= n_rows) return;

    const float* wb = (c8 < 64) ? (W0 + c8) : (W1b + (c8 - 64));

    const float* ap[4];
    #pragma unroll
    for (int i = 0; i < 4; i++) {
        int r = r0 + i;
        if (r > n_rows - 1) r = n_rows - 1;
        int ra = gather ? gather[r] : r;
        ap[i] = A + (size_t)ra * 128;
    }

    float acc[4][8];
    #pragma unroll
    for (int i = 0; i < 4; i++)
        #pragma unroll
        for (int j = 0; j < 8; j++) acc[i][j] = 0.f;

    for (int k = 0; k < 128; k += 4) {
        float4 av[4];
        #pragma unroll
        for (int i = 0; i < 4; i++) av[i] = *(const float4*)(ap[i] + k);

        const float* w = wb + (size_t)k * wstride;
        #pragma unroll
        for (int kk = 0; kk < 4; kk++) {
            float4 w0 = *(const float4*)(w);
            float4 w1 = *(const float4*)(w + 4);
            #pragma unroll
            for (int i = 0; i < 4; i++) {
                float s = (kk == 0) ? av[i].x : (kk == 1) ? av[i].y
                        : (kk == 2) ? av[i].z : av[i].w;
                acc[i][0] = fmaf(s, w0.x, acc[i][0]);
                acc[i][1] = fmaf(s, w0.y, acc[i][1]);
                acc[i][2] = fmaf(s, w0.z, acc[i][2]);
                acc[i][3] = fmaf(s, w0.w, acc[i][3]);
                acc[i][4] = fmaf(s, w1.x, acc[i][4]);
                acc[i][5] = fmaf(s, w1.y, acc[i][5]);
                acc[i][6] = fmaf(s, w1.z, acc[i][6]);
                acc[i][7] = fmaf(s, w1.w, acc[i][7]);
            }
            w += wstride;
        }
    }

    #pragma unroll
    for (int i = 0; i < 4; i++) {
        int r = r0 + i;
        if (r < n_rows) {
            uint4 pk;
            pk.x = f32_to_bf16_rne(acc[i][0]) | (f32_to_bf16_rne(acc[i][1]) << 16);
            pk.y = f32_to_bf16_rne(acc[i][2]) | (f32_to_bf16_rne(acc[i][3]) << 16);
            pk.z = f32_to_bf16_rne(acc[i][4]) | (f32_to_bf16_rne(acc[i][5]) << 16);
            pk.w = f32_to_bf16_rne(acc[i][6]) | (f32_to_bf16_rne(acc[i][7]) << 16);
            *(uint4*)(out + (size_t)r * 64 + (c8 >> 1)) = pk;
        }
    }
}

// ---------------------------------------------------------------------------
// Fused: CSR fill (latency-bound scatter) + layer-1 GEMM (VALU-bound).
// Role-interleaved blocks (every 9th = gemm) so both wave populations are
// co-resident and the CU overlaps VALU with scatter latency.
// ---------------------------------------------------------------------------
__global__ __launch_bounds__(256)
void fill_gemm_kernel(const int* __restrict__ row, const int* __restrict__ col,
                      int n_edges, const uint32* __restrict__ offs,
                      uint32* __restrict__ cursor, uint32* __restrict__ csr,
                      const float* __restrict__ A, const int* __restrict__ gather,
                      const float* __restrict__ W0, const float* __restrict__ W1b,
                      int wstride, uint32* __restrict__ out, int n_rows,
                      int n_gemm_blocks) {
    int bid = blockIdx.x;
    int q = bid / 9, r = bid % 9;
    bool is_gemm = (r == 0) && (q < n_gemm_blocks);
    if (is_gemm) {
        gemm_body(q, A, gather, W0, W1b, wstride, out, n_rows);
    } else {
        int before = q + (r ? 1 : 0);
        if (before > n_gemm_blocks) before = n_gemm_blocks;
        int fid = bid - before;
        int e = fid * 256 + (int)threadIdx.x;
        if (e < n_edges) {
            int c = col[e];
            uint32 p = offs[c] + atomicAdd(&cursor[c], 1u);
            csr[p] = (uint32)row[e];
        }
    }
}

// ---------------------------------------------------------------------------
// Fused layer-1 aggregation + layer-2 GEMM. 32 nodes per 256-thread block.
// Phase 1: one wave per node (8 sequential nodes/wave): gather bf16 hs rows,
//   h1 = relu(dis*(self+agg)+b1) -> LDS [32][132] f32 (pad 4 kills 4-way
//   ds_read_b128 bank conflicts in phase 2; row-starts land on bank 4*row%32).
// Phase 2: h2 = h1 @ [Wmu|Wlv] (2 rows x 8 cols/thread), bf16-pack -> out.
// Eliminates the bufB round-trip (51MB) and the separate gemm2 dispatch.
// ---------------------------------------------------------------------------
__global__ __launch_bounds__(256)
void agg1_gemm2_kernel(const uint32* __restrict__ hs, const uint32* __restrict__ offs,
                       const uint32* __restrict__ csr, const float* __restrict__ dis,
                       const float* __restrict__ b1,
                       const float* __restrict__ Wmu, const float* __restrict__ Wlv,
                       uint32* __restrict__ out, int n_nodes) {
    __shared__ float h1[32][132];
    int wave = threadIdx.x >> 6;
    int lane = threadIdx.x & 63;
    int base = blockIdx.x * 32;

    // ---- Phase 1: gather + relu, 8 nodes per wave ----
    for (int i = 0; i < 8; i++) {
        int nl = wave * 8 + i;
        int wid = base + nl;
        float ax = 0.f, ay = 0.f;
        if (wid < n_nodes) {
            float dv = dis[wid];
            uint32 sv = hs[(size_t)wid * 64 + lane];        // self-loop
            ax = dv * bf16_lo(sv); ay = dv * bf16_hi(sv);
            int beg = (int)offs[wid], end = (int)offs[wid + 1];
            int j = beg;
            for (; j + 8 <= end; j += 8) {
                uint32 e0 = csr[j],     e1 = csr[j + 1], e2 = csr[j + 2], e3 = csr[j + 3];
                uint32 e4 = csr[j + 4], e5 = csr[j + 5], e6 = csr[j + 6], e7 = csr[j + 7];
                float d0 = dis[e0], d1 = dis[e1], d2 = dis[e2], d3 = dis[e3];
                float d4 = dis[e4], d5 = dis[e5], d6 = dis[e6], d7 = dis[e7];
                uint32 v0 = hs[(size_t)e0 * 64 + lane];
                uint32 v1 = hs[(size_t)e1 * 64 + lane];
                uint32 v2 = hs[(size_t)e2 * 64 + lane];
                uint32 v3 = hs[(size_t)e3 * 64 + lane];
                uint32 v4 = hs[(size_t)e4 * 64 + lane];
                uint32 v5 = hs[(size_t)e5 * 64 + lane];
                uint32 v6 = hs[(size_t)e6 * 64 + lane];
                uint32 v7 = hs[(size_t)e7 * 64 + lane];
                ax = fmaf(d0, bf16_lo(v0), ax); ay = fmaf(d0, bf16_hi(v0), ay);
                ax = fmaf(d1, bf16_lo(v1), ax); ay = fmaf(d1, bf16_hi(v1), ay);
                ax = fmaf(d2, bf16_lo(v2), ax); ay = fmaf(d2, bf16_hi(v2), ay);
                ax = fmaf(d3, bf16_lo(v3), ax); ay = fmaf(d3, bf16_hi(v3), ay);
                ax = fmaf(d4, bf16_lo(v4), ax); ay = fmaf(d4, bf16_hi(v4), ay);
                ax = fmaf(d5, bf16_lo(v5), ax); ay = fmaf(d5, bf16_hi(v5), ay);
                ax = fmaf(d6, bf16_lo(v6), ax); ay = fmaf(d6, bf16_hi(v6), ay);
                ax = fmaf(d7, bf16_lo(v7), ax); ay = fmaf(d7, bf16_hi(v7), ay);
            }
            for (; j < end; ++j) {
                uint32 e = csr[j];
                float d = dis[e];
                uint32 v = hs[(size_t)e * 64 + lane];
                ax = fmaf(d, bf16_lo(v), ax); ay = fmaf(d, bf16_hi(v), ay);
            }
            float2 b = ((const float2*)b1)[lane];
            ax = fmaxf(fmaf(dv, ax, b.x), 0.f);
            ay = fmaxf(fmaf(dv, ay, b.y), 0.f);
        }
        *(float2*)&h1[nl][2 * lane] = make_float2(ax, ay);
    }
    __syncthreads();

    // ---- Phase 2: h2 = h1 @ [Wmu|Wlv], pack bf16 ----
    int rgrp = threadIdx.x >> 4;          // 0..15 -> rows 2*rgrp, 2*rgrp+1
    int c8   = (threadIdx.x & 15) * 8;    // col block
    const float* wb = (c8 < 64) ? (Wmu + c8) : (Wlv + (c8 - 64));

    float acc[2][8];
    #pragma unroll
    for (int i = 0; i < 2; i++)
        #pragma unroll
        for (int j = 0; j < 8; j++) acc[i][j] = 0.f;

    for (int k = 0; k < 128; k += 4) {
        float4 av0 = *(const float4*)&h1[2 * rgrp][k];
        float4 av1 = *(const float4*)&h1[2 * rgrp + 1][k];
        const float* w = wb + (size_t)k * 64;
        #pragma unroll
        for (int kk = 0; kk < 4; kk++) {
            float4 w0 = *(const float4*)(w);
            float4 w1 = *(const float4*)(w + 4);
            float s0 = (kk == 0) ? av0.x : (kk == 1) ? av0.y : (kk == 2) ? av0.z : av0.w;
            float s1 = (kk == 0) ? av1.x : (kk == 1) ? av1.y : (kk == 2) ? av1.z : av1.w;
            acc[0][0] = fmaf(s0, w0.x, acc[0][0]); acc[1][0] = fmaf(s1, w0.x, acc[1][0]);
            acc[0][1] = fmaf(s0, w0.y, acc[0][1]); acc[1][1] = fmaf(s1, w0.y, acc[1][1]);
            acc[0][2] = fmaf(s0, w0.z, acc[0][2]); acc[1][2] = fmaf(s1, w0.z, acc[1][2]);
            acc[0][3] = fmaf(s0, w0.w, acc[0][3]); acc[1][3] = fmaf(s1, w0.w, acc[1][3]);
            acc[0][4] = fmaf(s0, w1.x, acc[0][4]); acc[1][4] = fmaf(s1, w1.x, acc[1][4]);
            acc[0][5] = fmaf(s0, w1.y, acc[0][5]); acc[1][5] = fmaf(s1, w1.y, acc[1][5]);
            acc[0][6] = fmaf(s0, w1.z, acc[0][6]); acc[1][6] = fmaf(s1, w1.z, acc[1][6]);
            acc[0][7] = fmaf(s0, w1.w, acc[0][7]); acc[1][7] = fmaf(s1, w1.w, acc[1][7]);
            w += 64;
        }
    }

    #pragma unroll
    for (int i = 0; i < 2; i++) {
        int r = base + 2 * rgrp + i;
        if (r < n_nodes) {
            uint4 pk;
            pk.x = f32_to_bf16_rne(acc[i][0]) | (f32_to_bf16_rne(acc[i][1]) << 16);
            pk.y = f32_to_bf16_rne(acc[i][2]) | (f32_to_bf16_rne(acc[i][3]) << 16);
            pk.z = f32_to_bf16_rne(acc[i][4]) | (f32_to_bf16_rne(acc[i][5]) << 16);
            pk.w = f32_to_bf16_rne(acc[i][6]) | (f32_to_bf16_rne(acc[i][7]) << 16);
            *(uint4*)(out + (size_t)r * 64 + (c8 >> 1)) = pk;
        }
    }
}

// Layer 2 aggregation: feats 0..63 -> mu (+b_mu), 64..127 -> logvar (+b_logvar).
__global__ __launch_bounds__(256)
void agg_out_kernel(const uint32* __restrict__ hs, const uint32* __restrict__ offs,
                    const uint32* __restrict__ csr, const float* __restrict__ dis,
                    const float* __restrict__ bmu, const float* __restrict__ blv,
                    float* __restrict__ out_mu, float* __restrict__ out_lv, int n_nodes) {
    int wid = (blockIdx.x * 256 + (int)threadIdx.x) >> 6;
    int lane = threadIdx.x & 63;
    if (wid >= n_nodes) return;

    float dv = dis[wid];
    uint32 sv = hs[(size_t)wid * 64 + lane];
    float ax = dv * bf16_lo(sv), ay = dv * bf16_hi(sv);
    int beg = (int)offs[wid], end = (int)offs[wid + 1];

    int j = beg;
    for (; j + 8 <= end; j += 8) {
        uint32 e0 = csr[j],     e1 = csr[j + 1], e2 = csr[j + 2], e3 = csr[j + 3];
        uint32 e4 = csr[j + 4], e5 = csr[j + 5], e6 = csr[j + 6], e7 = csr[j + 7];
        float d0 = dis[e0], d1 = dis[e1], d2 = dis[e2], d3 = dis[e3];
        float d4 = dis[e4], d5 = dis[e5], d6 = dis[e6], d7 = dis[e7];
        uint32 v0 = hs[(size_t)e0 * 64 + lane];
        uint32 v1 = hs[(size_t)e1 * 64 + lane];
        uint32 v2 = hs[(size_t)e2 * 64 + lane];
        uint32 v3 = hs[(size_t)e3 * 64 + lane];
        uint32 v4 = hs[(size_t)e4 * 64 + lane];
        uint32 v5 = hs[(size_t)e5 * 64 + lane];
        uint32 v6 = hs[(size_t)e6 * 64 + lane];
        uint32 v7 = hs[(size_t)e7 * 64 + lane];
        ax = fmaf(d0, bf16_lo(v0), ax); ay = fmaf(d0, bf16_hi(v0), ay);
        ax = fmaf(d1, bf16_lo(v1), ax); ay = fmaf(d1, bf16_hi(v1), ay);
        ax = fmaf(d2, bf16_lo(v2), ax); ay = fmaf(d2, bf16_hi(v2), ay);
        ax = fmaf(d3, bf16_lo(v3), ax); ay = fmaf(d3, bf16_hi(v3), ay);
        ax = fmaf(d4, bf16_lo(v4), ax); ay = fmaf(d4, bf16_hi(v4), ay);
        ax = fmaf(d5, bf16_lo(v5), ax); ay = fmaf(d5, bf16_hi(v5), ay);
        ax = fmaf(d6, bf16_lo(v6), ax); ay = fmaf(d6, bf16_hi(v6), ay);
        ax = fmaf(d7, bf16_lo(v7), ax); ay = fmaf(d7, bf16_hi(v7), ay);
    }
    for (; j < end; ++j) {
        uint32 e = csr[j];
        float d = dis[e];
        uint32 v = hs[(size_t)e * 64 + lane];
        ax = fmaf(d, bf16_lo(v), ax); ay = fmaf(d, bf16_hi(v), ay);
    }

    if (lane < 32) {
        float2 b = ((const float2*)bmu)[lane];
        float2 o = make_float2(fmaf(dv, ax, b.x), fmaf(dv, ay, b.y));
        ((float2*)out_mu)[(size_t)wid * 32 + lane] = o;
    } else {
        int l2 = lane - 32;
        float2 b = ((const float2*)blv)[l2];
        float2 o = make_float2(fmaf(dv, ax, b.x), fmaf(dv, ay, b.y));
        ((float2*)out_lv)[(size_t)wid * 32 + l2] = o;
    }
}

// ---------------------------------------------------------------------------

extern "C" void kernel_launch(void* const* d_in, const int* in_sizes, int n_in,
                              void* d_out, int out_size, void* d_ws, size_t ws_size,
                              hipStream_t stream) {
    const int*   x   = (const int*)d_in[0];
    const int*   ei  = (const int*)d_in[1];
    const float* emb = (const float*)d_in[2];
    const float* W1  = (const float*)d_in[3];
    const float* b1  = (const float*)d_in[4];
    const float* Wmu = (const float*)d_in[5];
    const float* bmu = (const float*)d_in[6];
    const float* Wlv = (const float*)d_in[7];
    const float* blv = (const float*)d_in[8];

    int n_nodes = in_sizes[0];
    int n_edges = in_sizes[1] / 2;
    const int* row = ei;              // source nodes
    const int* col = ei + n_edges;    // target nodes (aggregation index)

    // Workspace carve-out (all 256B-aligned).
    char* wp = (char*)d_ws;
    auto carve = [&wp](size_t bytes) -> char* {
        char* p = wp;
        wp += (bytes + 255) & ~(size_t)255;
        return p;
    };
    int nb = (n_nodes + 255) / 256;   // scan blocks (196 for 50k, <= 1024)

    uint32* cnt     = (uint32*)carve((size_t)n_nodes * 4);
    uint32* cursor  = (uint32*)carve((size_t)n_nodes * 4);
    uint32* offs    = (uint32*)carve(((size_t)n_nodes + 1) * 4);
    uint32* partial = (uint32*)carve((size_t)n_nodes * 4);
    uint32* bsums   = (uint32*)carve((size_t)nb * 4);
    uint32* boffs   = (uint32*)carve((size_t)nb * 4);
    float*  dis     = (float*) carve((size_t)n_nodes * 4);
    uint32* csr     = (uint32*)carve((size_t)n_edges * 4);
    uint32* bufA    = (uint32*)carve((size_t)n_nodes * 64 * 4);    // hs, packed bf16
    uint32* bufC    = (uint32*)carve((size_t)n_nodes * 64 * 4);    // h2, packed bf16

    int gb_e = (n_edges + 255) / 256;            // fill blocks (6250)
    int gemm_blocks = (n_nodes + 63) / 64;       // 782
    int agg_blocks  = (n_nodes + 3) / 4;
    int ag_blocks   = (n_nodes + 31) / 32;       // fused agg1+gemm2 blocks

    hipMemsetAsync(cnt, 0, (size_t)n_nodes * 4, stream);
    hipLaunchKernelGGL(count_kernel, dim3(gb_e), dim3(256), 0, stream, col, n_edges, cnt);
    hipLaunchKernelGGL(scan_blk_kernel, dim3(nb), dim3(256), 0, stream, cnt, partial, bsums, n_nodes);
    hipLaunchKernelGGL(scan_sums_kernel, dim3(1), dim3(1024), 0, stream, bsums, boffs, nb);
    hipLaunchKernelGGL(scan_add_kernel, dim3(nb), dim3(256), 0, stream,
                       partial, boffs, cnt, offs, dis, cursor, n_nodes, n_edges);

    // Fused: CSR fill + layer-1 GEMM (hs = bf16(emb[x] @ W1), unscaled)
    hipLaunchKernelGGL(fill_gemm_kernel, dim3(gb_e + gemm_blocks), dim3(256), 0, stream,
                       row, col, n_edges, offs, cursor, csr,
                       emb, x, W1, W1 + 64, 128, bufA, n_nodes, gemm_blocks);

    // Fused: layer-1 aggregation + relu + layer-2 GEMM (bufA -> bufC; distinct
    // buffers — writing bufA in place would race with other blocks' gathers).
    hipLaunchKernelGGL(agg1_gemm2_kernel, dim3(ag_blocks), dim3(256), 0, stream,
                       bufA, offs, csr, dis, b1, Wmu, Wlv, bufC, n_nodes);

    float* out_mu = (float*)d_out;
    float* out_lv = out_mu + (size_t)n_nodes * 64;
    hipLaunchKernelGGL(agg_out_kernel, dim3(agg_blocks), dim3(256), 0, stream,
                       bufC, offs, csr, dis, bmu, blv, out_mu, out_lv, n_nodes);
}

// Round 14
// 422.075 us; speedup vs baseline: 1.7731x; 1.0743x over previous
//
#include <hip/hip_runtime.h>
#include <hip/hip_bf16.h>

typedef unsigned int uint32;

// ---------------------------------------------------------------------------
// Graph preprocessing: degree count (+ per-edge rank) -> hierarchical scan
// ---------------------------------------------------------------------------

// rank[e] = position of edge e within its target node's CSR segment.
// The atomic was already needed for counting; returning the old value is free.
__global__ __launch_bounds__(256)
void count_rank_kernel(const int* __restrict__ col, int n_edges,
                       uint32* __restrict__ cnt, uint32* __restrict__ rank) {
    int e = blockIdx.x * 256 + threadIdx.x;
    if (e < n_edges) rank[e] = atomicAdd(&cnt[col[e]], 1u);
}

// Stage 1: per-block (256 elems) exclusive scan + per-block sum.
__global__ __launch_bounds__(256)
void scan_blk_kernel(const uint32* __restrict__ cnt, uint32* __restrict__ partial,
                     uint32* __restrict__ blk_sums, int n) {
    __shared__ uint32 sh[256];
    int i = blockIdx.x * 256 + (int)threadIdx.x;
    uint32 v = (i < n) ? cnt[i] : 0u;
    sh[threadIdx.x] = v;
    __syncthreads();
    for (int off = 1; off < 256; off <<= 1) {
        uint32 t = (threadIdx.x >= (unsigned)off) ? sh[threadIdx.x - off] : 0u;
        __syncthreads();
        sh[threadIdx.x] += t;
        __syncthreads();
    }
    if (i < n) partial[i] = sh[threadIdx.x] - v;      // exclusive within block
    if (threadIdx.x == 255) blk_sums[blockIdx.x] = sh[255];
}

// Stage 2: one block scans the block sums (nb <= 1024).
__global__ __launch_bounds__(1024)
void scan_sums_kernel(const uint32* __restrict__ blk_sums, uint32* __restrict__ blk_offs, int nb) {
    __shared__ uint32 sh[1024];
    uint32 v = ((int)threadIdx.x < nb) ? blk_sums[threadIdx.x] : 0u;
    sh[threadIdx.x] = v;
    __syncthreads();
    for (int off = 1; off < 1024; off <<= 1) {
        uint32 t = (threadIdx.x >= (unsigned)off) ? sh[threadIdx.x - off] : 0u;
        __syncthreads();
        sh[threadIdx.x] += t;
        __syncthreads();
    }
    if ((int)threadIdx.x < nb) blk_offs[threadIdx.x] = sh[threadIdx.x] - v;
}

// Stage 3: offs = partial + blk_offs; fused dis = rsqrt(deg+1).
__global__ __launch_bounds__(256)
void scan_add_kernel(const uint32* __restrict__ partial, const uint32* __restrict__ blk_offs,
                     const uint32* __restrict__ cnt, uint32* __restrict__ offs,
                     float* __restrict__ dis, int n, int n_edges) {
    int i = blockIdx.x * 256 + (int)threadIdx.x;
    if (i < n) {
        offs[i] = partial[i] + blk_offs[blockIdx.x];
        dis[i] = rsqrtf((float)(cnt[i] + 1u));   // self-loop => deg >= 1
    }
    if (i == 0) offs[n] = (uint32)n_edges;       // sum of cnt == n_edges
}

// ---------------------------------------------------------------------------
// bf16 helpers (RNE, deterministic)
// ---------------------------------------------------------------------------
static __device__ __forceinline__ uint32 f32_to_bf16_rne(float f) {
    uint32 u = __float_as_uint(f);
    return (u + 0x7fffu + ((u >> 16) & 1u)) >> 16;
}
static __device__ __forceinline__ float bf16_lo(uint32 v) {   // feats 2*lane
    return __uint_as_float(v << 16);
}
static __device__ __forceinline__ float bf16_hi(uint32 v) {   // feats 2*lane+1
    return __uint_as_float(v & 0xffff0000u);
}

// ---------------------------------------------------------------------------
// GEMM body: hs[r][c] = sum_k A[gather(r)][k] * W[k][c]   (UNscaled; dis is
// applied per-edge in the agg kernels). Packed-bf16 output (row = 256B).
// 4 rows x 8 cols per thread; 64 rows per 256-thread block.
// ---------------------------------------------------------------------------
static __device__ __forceinline__
void gemm_body(int gbid, const float* __restrict__ A, const int* __restrict__ gather,
               const float* __restrict__ W0, const float* __restrict__ W1b,
               int wstride, uint32* __restrict__ out, int n_rows) {
    int grp = threadIdx.x >> 4;            // 0..15
    int c8  = (threadIdx.x & 15) * 8;      // col block
    int r0  = gbid * 64 + grp * 4;         // first of 4 rows
    if (r0 >= n_rows) return;

    const float* wb = (c8 < 64) ? (W0 + c8) : (W1b + (c8 - 64));

    const float* ap[4];
    #pragma unroll
    for (int i = 0; i < 4; i++) {
        int r = r0 + i;
        if (r > n_rows - 1) r = n_rows - 1;
        int ra = gather ? gather[r] : r;
        ap[i] = A + (size_t)ra * 128;
    }

    float acc[4][8];
    #pragma unroll
    for (int i = 0; i < 4; i++)
        #pragma unroll
        for (int j = 0; j < 8; j++) acc[i][j] = 0.f;

    for (int k = 0; k < 128; k += 4) {
        float4 av[4];
        #pragma unroll
        for (int i = 0; i < 4; i++) av[i] = *(const float4*)(ap[i] + k);

        const float* w = wb + (size_t)k * wstride;
        #pragma unroll
        for (int kk = 0; kk < 4; kk++) {
            float4 w0 = *(const float4*)(w);
            float4 w1 = *(const float4*)(w + 4);
            #pragma unroll
            for (int i = 0; i < 4; i++) {
                float s = (kk == 0) ? av[i].x : (kk == 1) ? av[i].y
                        : (kk == 2) ? av[i].z : av[i].w;
                acc[i][0] = fmaf(s, w0.x, acc[i][0]);
                acc[i][1] = fmaf(s, w0.y, acc[i][1]);
                acc[i][2] = fmaf(s, w0.z, acc[i][2]);
                acc[i][3] = fmaf(s, w0.w, acc[i][3]);
                acc[i][4] = fmaf(s, w1.x, acc[i][4]);
                acc[i][5] = fmaf(s, w1.y, acc[i][5]);
                acc[i][6] = fmaf(s, w1.z, acc[i][6]);
                acc[i][7] = fmaf(s, w1.w, acc[i][7]);
            }
            w += wstride;
        }
    }

    #pragma unroll
    for (int i = 0; i < 4; i++) {
        int r = r0 + i;
        if (r < n_rows) {
            uint4 pk;
            pk.x = f32_to_bf16_rne(acc[i][0]) | (f32_to_bf16_rne(acc[i][1]) << 16);
            pk.y = f32_to_bf16_rne(acc[i][2]) | (f32_to_bf16_rne(acc[i][3]) << 16);
            pk.z = f32_to_bf16_rne(acc[i][4]) | (f32_to_bf16_rne(acc[i][5]) << 16);
            pk.w = f32_to_bf16_rne(acc[i][6]) | (f32_to_bf16_rne(acc[i][7]) << 16);
            *(uint4*)(out + (size_t)r * 64 + (c8 >> 1)) = pk;
        }
    }
}

// ---------------------------------------------------------------------------
// Fused: CSR fill (pure scatter, NO atomics — rank precomputed) + layer-1 GEMM.
// The store address offs[c]+rank[e] has no value dependency: waves issue the
// store and retire instead of stalling on an atomic round-trip per edge.
// Role-interleaved blocks (every 9th = gemm) keep both populations co-resident.
// ---------------------------------------------------------------------------
__global__ __launch_bounds__(256)
void fill_gemm_kernel(const int* __restrict__ row, const int* __restrict__ col,
                      const uint32* __restrict__ rank, int n_edges,
                      const uint32* __restrict__ offs, uint32* __restrict__ csr,
                      const float* __restrict__ A, const int* __restrict__ gather,
                      const float* __restrict__ W0, const float* __restrict__ W1b,
                      int wstride, uint32* __restrict__ out, int n_rows,
                      int n_gemm_blocks) {
    int bid = blockIdx.x;
    int q = bid / 9, r = bid % 9;
    bool is_gemm = (r == 0) && (q < n_gemm_blocks);
    if (is_gemm) {
        gemm_body(q, A, gather, W0, W1b, wstride, out, n_rows);
    } else {
        int before = q + (r ? 1 : 0);
        if (before > n_gemm_blocks) before = n_gemm_blocks;
        int fid = bid - before;
        int e = fid * 256 + (int)threadIdx.x;
        if (e < n_edges) {
            int c = col[e];
            csr[offs[c] + rank[e]] = (uint32)row[e];
        }
    }
}

// ---------------------------------------------------------------------------
// Fused layer-1 aggregation + layer-2 GEMM. 32 nodes per 256-thread block.
// Phase 1: one wave per node (8 sequential nodes/wave): gather bf16 hs rows,
//   h1 = relu(dis*(self+agg)+b1) -> LDS [32][132] f32 (pad 4 kills 4-way
//   ds_read_b128 bank conflicts in phase 2).
// Phase 2: h2 = h1 @ [Wmu|Wlv] (2 rows x 8 cols/thread), bf16-pack -> out.
// ---------------------------------------------------------------------------
__global__ __launch_bounds__(256)
void agg1_gemm2_kernel(const uint32* __restrict__ hs, const uint32* __restrict__ offs,
                       const uint32* __restrict__ csr, const float* __restrict__ dis,
                       const float* __restrict__ b1,
                       const float* __restrict__ Wmu, const float* __restrict__ Wlv,
                       uint32* __restrict__ out, int n_nodes) {
    __shared__ float h1[32][132];
    int wave = threadIdx.x >> 6;
    int lane = threadIdx.x & 63;
    int base = blockIdx.x * 32;

    // ---- Phase 1: gather + relu, 8 nodes per wave ----
    for (int i = 0; i < 8; i++) {
        int nl = wave * 8 + i;
        int wid = base + nl;
        float ax = 0.f, ay = 0.f;
        if (wid < n_nodes) {
            float dv = dis[wid];
            uint32 sv = hs[(size_t)wid * 64 + lane];        // self-loop
            ax = dv * bf16_lo(sv); ay = dv * bf16_hi(sv);
            int beg = (int)offs[wid], end = (int)offs[wid + 1];
            int j = beg;
            for (; j + 8 <= end; j += 8) {
                uint32 e0 = csr[j],     e1 = csr[j + 1], e2 = csr[j + 2], e3 = csr[j + 3];
                uint32 e4 = csr[j + 4], e5 = csr[j + 5], e6 = csr[j + 6], e7 = csr[j + 7];
                float d0 = dis[e0], d1 = dis[e1], d2 = dis[e2], d3 = dis[e3];
                float d4 = dis[e4], d5 = dis[e5], d6 = dis[e6], d7 = dis[e7];
                uint32 v0 = hs[(size_t)e0 * 64 + lane];
                uint32 v1 = hs[(size_t)e1 * 64 + lane];
                uint32 v2 = hs[(size_t)e2 * 64 + lane];
                uint32 v3 = hs[(size_t)e3 * 64 + lane];
                uint32 v4 = hs[(size_t)e4 * 64 + lane];
                uint32 v5 = hs[(size_t)e5 * 64 + lane];
                uint32 v6 = hs[(size_t)e6 * 64 + lane];
                uint32 v7 = hs[(size_t)e7 * 64 + lane];
                ax = fmaf(d0, bf16_lo(v0), ax); ay = fmaf(d0, bf16_hi(v0), ay);
                ax = fmaf(d1, bf16_lo(v1), ax); ay = fmaf(d1, bf16_hi(v1), ay);
                ax = fmaf(d2, bf16_lo(v2), ax); ay = fmaf(d2, bf16_hi(v2), ay);
                ax = fmaf(d3, bf16_lo(v3), ax); ay = fmaf(d3, bf16_hi(v3), ay);
                ax = fmaf(d4, bf16_lo(v4), ax); ay = fmaf(d4, bf16_hi(v4), ay);
                ax = fmaf(d5, bf16_lo(v5), ax); ay = fmaf(d5, bf16_hi(v5), ay);
                ax = fmaf(d6, bf16_lo(v6), ax); ay = fmaf(d6, bf16_hi(v6), ay);
                ax = fmaf(d7, bf16_lo(v7), ax); ay = fmaf(d7, bf16_hi(v7), ay);
            }
            for (; j < end; ++j) {
                uint32 e = csr[j];
                float d = dis[e];
                uint32 v = hs[(size_t)e * 64 + lane];
                ax = fmaf(d, bf16_lo(v), ax); ay = fmaf(d, bf16_hi(v), ay);
            }
            float2 b = ((const float2*)b1)[lane];
            ax = fmaxf(fmaf(dv, ax, b.x), 0.f);
            ay = fmaxf(fmaf(dv, ay, b.y), 0.f);
        }
        *(float2*)&h1[nl][2 * lane] = make_float2(ax, ay);
    }
    __syncthreads();

    // ---- Phase 2: h2 = h1 @ [Wmu|Wlv], pack bf16 ----
    int rgrp = threadIdx.x >> 4;          // 0..15 -> rows 2*rgrp, 2*rgrp+1
    int c8   = (threadIdx.x & 15) * 8;    // col block
    const float* wb = (c8 < 64) ? (Wmu + c8) : (Wlv + (c8 - 64));

    float acc[2][8];
    #pragma unroll
    for (int i = 0; i < 2; i++)
        #pragma unroll
        for (int j = 0; j < 8; j++) acc[i][j] = 0.f;

    for (int k = 0; k < 128; k += 4) {
        float4 av0 = *(const float4*)&h1[2 * rgrp][k];
        float4 av1 = *(const float4*)&h1[2 * rgrp + 1][k];
        const float* w = wb + (size_t)k * 64;
        #pragma unroll
        for (int kk = 0; kk < 4; kk++) {
            float4 w0 = *(const float4*)(w);
            float4 w1 = *(const float4*)(w + 4);
            float s0 = (kk == 0) ? av0.x : (kk == 1) ? av0.y : (kk == 2) ? av0.z : av0.w;
            float s1 = (kk == 0) ? av1.x : (kk == 1) ? av1.y : (kk == 2) ? av1.z : av1.w;
            acc[0][0] = fmaf(s0, w0.x, acc[0][0]); acc[1][0] = fmaf(s1, w0.x, acc[1][0]);
            acc[0][1] = fmaf(s0, w0.y, acc[0][1]); acc[1][1] = fmaf(s1, w0.y, acc[1][1]);
            acc[0][2] = fmaf(s0, w0.z, acc[0][2]); acc[1][2] = fmaf(s1, w0.z, acc[1][2]);
            acc[0][3] = fmaf(s0, w0.w, acc[0][3]); acc[1][3] = fmaf(s1, w0.w, acc[1][3]);
            acc[0][4] = fmaf(s0, w1.x, acc[0][4]); acc[1][4] = fmaf(s1, w1.x, acc[1][4]);
            acc[0][5] = fmaf(s0, w1.y, acc[0][5]); acc[1][5] = fmaf(s1, w1.y, acc[1][5]);
            acc[0][6] = fmaf(s0, w1.z, acc[0][6]); acc[1][6] = fmaf(s1, w1.z, acc[1][6]);
            acc[0][7] = fmaf(s0, w1.w, acc[0][7]); acc[1][7] = fmaf(s1, w1.w, acc[1][7]);
            w += 64;
        }
    }

    #pragma unroll
    for (int i = 0; i < 2; i++) {
        int r = base + 2 * rgrp + i;
        if (r < n_nodes) {
            uint4 pk;
            pk.x = f32_to_bf16_rne(acc[i][0]) | (f32_to_bf16_rne(acc[i][1]) << 16);
            pk.y = f32_to_bf16_rne(acc[i][2]) | (f32_to_bf16_rne(acc[i][3]) << 16);
            pk.z = f32_to_bf16_rne(acc[i][4]) | (f32_to_bf16_rne(acc[i][5]) << 16);
            pk.w = f32_to_bf16_rne(acc[i][6]) | (f32_to_bf16_rne(acc[i][7]) << 16);
            *(uint4*)(out + (size_t)r * 64 + (c8 >> 1)) = pk;
        }
    }
}

// Layer 2 aggregation: feats 0..63 -> mu (+b_mu), 64..127 -> logvar (+b_logvar).
__global__ __launch_bounds__(256)
void agg_out_kernel(const uint32* __restrict__ hs, const uint32* __restrict__ offs,
                    const uint32* __restrict__ csr, const float* __restrict__ dis,
                    const float* __restrict__ bmu, const float* __restrict__ blv,
                    float* __restrict__ out_mu, float* __restrict__ out_lv, int n_nodes) {
    int wid = (blockIdx.x * 256 + (int)threadIdx.x) >> 6;
    int lane = threadIdx.x & 63;
    if (wid >= n_nodes) return;

    float dv = dis[wid];
    uint32 sv = hs[(size_t)wid * 64 + lane];
    float ax = dv * bf16_lo(sv), ay = dv * bf16_hi(sv);
    int beg = (int)offs[wid], end = (int)offs[wid + 1];

    int j = beg;
    for (; j + 8 <= end; j += 8) {
        uint32 e0 = csr[j],     e1 = csr[j + 1], e2 = csr[j + 2], e3 = csr[j + 3];
        uint32 e4 = csr[j + 4], e5 = csr[j + 5], e6 = csr[j + 6], e7 = csr[j + 7];
        float d0 = dis[e0], d1 = dis[e1], d2 = dis[e2], d3 = dis[e3];
        float d4 = dis[e4], d5 = dis[e5], d6 = dis[e6], d7 = dis[e7];
        uint32 v0 = hs[(size_t)e0 * 64 + lane];
        uint32 v1 = hs[(size_t)e1 * 64 + lane];
        uint32 v2 = hs[(size_t)e2 * 64 + lane];
        uint32 v3 = hs[(size_t)e3 * 64 + lane];
        uint32 v4 = hs[(size_t)e4 * 64 + lane];
        uint32 v5 = hs[(size_t)e5 * 64 + lane];
        uint32 v6 = hs[(size_t)e6 * 64 + lane];
        uint32 v7 = hs[(size_t)e7 * 64 + lane];
        ax = fmaf(d0, bf16_lo(v0), ax); ay = fmaf(d0, bf16_hi(v0), ay);
        ax = fmaf(d1, bf16_lo(v1), ax); ay = fmaf(d1, bf16_hi(v1), ay);
        ax = fmaf(d2, bf16_lo(v2), ax); ay = fmaf(d2, bf16_hi(v2), ay);
        ax = fmaf(d3, bf16_lo(v3), ax); ay = fmaf(d3, bf16_hi(v3), ay);
        ax = fmaf(d4, bf16_lo(v4), ax); ay = fmaf(d4, bf16_hi(v4), ay);
        ax = fmaf(d5, bf16_lo(v5), ax); ay = fmaf(d5, bf16_hi(v5), ay);
        ax = fmaf(d6, bf16_lo(v6), ax); ay = fmaf(d6, bf16_hi(v6), ay);
        ax = fmaf(d7, bf16_lo(v7), ax); ay = fmaf(d7, bf16_hi(v7), ay);
    }
    for (; j < end; ++j) {
        uint32 e = csr[j];
        float d = dis[e];
        uint32 v = hs[(size_t)e * 64 + lane];
        ax = fmaf(d, bf16_lo(v), ax); ay = fmaf(d, bf16_hi(v), ay);
    }

    if (lane < 32) {
        float2 b = ((const float2*)bmu)[lane];
        float2 o = make_float2(fmaf(dv, ax, b.x), fmaf(dv, ay, b.y));
        ((float2*)out_mu)[(size_t)wid * 32 + lane] = o;
    } else {
        int l2 = lane - 32;
        float2 b = ((const float2*)blv)[l2];
        float2 o = make_float2(fmaf(dv, ax, b.x), fmaf(dv, ay, b.y));
        ((float2*)out_lv)[(size_t)wid * 32 + l2] = o;
    }
}

// ---------------------------------------------------------------------------

extern "C" void kernel_launch(void* const* d_in, const int* in_sizes, int n_in,
                              void* d_out, int out_size, void* d_ws, size_t ws_size,
                              hipStream_t stream) {
    const int*   x   = (const int*)d_in[0];
    const int*   ei  = (const int*)d_in[1];
    const float* emb = (const float*)d_in[2];
    const float* W1  = (const float*)d_in[3];
    const float* b1  = (const float*)d_in[4];
    const float* Wmu = (const float*)d_in[5];
    const float* bmu = (const float*)d_in[6];
    const float* Wlv = (const float*)d_in[7];
    const float* blv = (const float*)d_in[8];

    int n_nodes = in_sizes[0];
    int n_edges = in_sizes[1] / 2;
    const int* row = ei;              // source nodes
    const int* col = ei + n_edges;    // target nodes (aggregation index)

    // Workspace carve-out (all 256B-aligned).
    char* wp = (char*)d_ws;
    auto carve = [&wp](size_t bytes) -> char* {
        char* p = wp;
        wp += (bytes + 255) & ~(size_t)255;
        return p;
    };
    int nb = (n_nodes + 255) / 256;   // scan blocks (196 for 50k, <= 1024)

    uint32* cnt     = (uint32*)carve((size_t)n_nodes * 4);
    uint32* offs    = (uint32*)carve(((size_t)n_nodes + 1) * 4);
    uint32* partial = (uint32*)carve((size_t)n_nodes * 4);
    uint32* bsums   = (uint32*)carve((size_t)nb * 4);
    uint32* boffs   = (uint32*)carve((size_t)nb * 4);
    float*  dis     = (float*) carve((size_t)n_nodes * 4);
    uint32* rank    = (uint32*)carve((size_t)n_edges * 4);
    uint32* csr     = (uint32*)carve((size_t)n_edges * 4);
    uint32* bufA    = (uint32*)carve((size_t)n_nodes * 64 * 4);    // hs, packed bf16
    uint32* bufC    = (uint32*)carve((size_t)n_nodes * 64 * 4);    // h2, packed bf16

    int gb_e = (n_edges + 255) / 256;            // fill blocks (6250)
    int gemm_blocks = (n_nodes + 63) / 64;       // 782
    int agg_blocks  = (n_nodes + 3) / 4;
    int ag_blocks   = (n_nodes + 31) / 32;       // fused agg1+gemm2 blocks

    hipMemsetAsync(cnt, 0, (size_t)n_nodes * 4, stream);
    hipLaunchKernelGGL(count_rank_kernel, dim3(gb_e), dim3(256), 0, stream,
                       col, n_edges, cnt, rank);
    hipLaunchKernelGGL(scan_blk_kernel, dim3(nb), dim3(256), 0, stream, cnt, partial, bsums, n_nodes);
    hipLaunchKernelGGL(scan_sums_kernel, dim3(1), dim3(1024), 0, stream, bsums, boffs, nb);
    hipLaunchKernelGGL(scan_add_kernel, dim3(nb), dim3(256), 0, stream,
                       partial, boffs, cnt, offs, dis, n_nodes, n_edges);

    // Fused: CSR fill (atomic-free scatter) + layer-1 GEMM (hs = bf16(emb[x] @ W1))
    hipLaunchKernelGGL(fill_gemm_kernel, dim3(gb_e + gemm_blocks), dim3(256), 0, stream,
                       row, col, rank, n_edges, offs, csr,
                       emb, x, W1, W1 + 64, 128, bufA, n_nodes, gemm_blocks);

    // Fused: layer-1 aggregation + relu + layer-2 GEMM (bufA -> bufC)
    hipLaunchKernelGGL(agg1_gemm2_kernel, dim3(ag_blocks), dim3(256), 0, stream,
                       bufA, offs, csr, dis, b1, Wmu, Wlv, bufC, n_nodes);

    float* out_mu = (float*)d_out;
    float* out_lv = out_mu + (size_t)n_nodes * 64;
    hipLaunchKernelGGL(agg_out_kernel, dim3(agg_blocks), dim3(256), 0, stream,
                       bufC, offs, csr, dis, bmu, blv, out_mu, out_lv, n_nodes);
}